// Round 12
// baseline (634.302 us; speedup 1.0000x reference)
//
#include <hip/hip_runtime.h>
#include <hip/hip_bf16.h>

// ---------------------------------------------------------------------------
// 3-layer GAT forward (PyG GATConv, eval) on MI355X.
// Agg = r5's measured-best structure: fp32 h~ table, precomputed per-edge
// weights w[e][8] (edgew_k), chunk-split grid (wave = node x channel-chunk,
// float4/lane), inline lead-lane denominators, split-bf16 epilogue, 20 VGPR.
// GEMM: split-bf16 MFMA (3 products ~ fp32), fp32 output.
// Alphas: x@(W@a) identity (alpha1_k) and h@(W@a) via alphaproj_k.
// CSR: (dst, src-block)-keyed histogram + 3-stage hierarchical scan.
// ---------------------------------------------------------------------------

#define NFEAT 129
#define MPAD  30080   // 235 * 128
#define BLKSH 11
#define KPD   16

typedef __attribute__((ext_vector_type(8))) short short8v;
typedef __attribute__((ext_vector_type(8))) unsigned short u16x8;
typedef __attribute__((ext_vector_type(8))) __bf16 bf16x8;
typedef __attribute__((ext_vector_type(4))) float f32x4;
typedef unsigned short u16;

union FragU { short8v s; bf16x8 b; };

__device__ inline u16 f2bf(float x) {
    unsigned u = __builtin_bit_cast(unsigned, x);
    unsigned r = (u + 0x7fffu + ((u >> 16) & 1u)) >> 16;
    return (u16)r;
}
__device__ inline float bf2f(u16 b) {
    unsigned u = ((unsigned)b) << 16;
    return __builtin_bit_cast(float, u);
}

// ---------------- CSR build (keyed by dst*KPD + src-block) ----------------

__global__ __launch_bounds__(256) void hist_k(const int* __restrict__ src,
                                              const int* __restrict__ dst,
                                              int* __restrict__ cnt, int E, int n) {
    int e = blockIdx.x * 256 + threadIdx.x;
    if (e < E + n) {
        int s, d;
        if (e < E) { s = src[e]; d = dst[e]; }
        else       { s = d = e - E; }
        atomicAdd(&cnt[d * KPD + (s >> BLKSH)], 1);
    }
}

__global__ __launch_bounds__(256) void bsum_k(const int* __restrict__ cnt,
                                              int* __restrict__ bsum, int nk) {
    __shared__ int sh[256];
    int t = threadIdx.x, idx = blockIdx.x * 256 + t;
    sh[t] = (idx < nk) ? cnt[idx] : 0;
    __syncthreads();
    for (int o = 128; o; o >>= 1) {
        if (t < o) sh[t] += sh[t + o];
        __syncthreads();
    }
    if (t == 0) bsum[blockIdx.x] = sh[0];
}

__global__ __launch_bounds__(1024) void bscan_k(const int* __restrict__ bsum,
                                                int* __restrict__ bofs, int nb) {
    __shared__ int part[1024];
    int t = threadIdx.x;
    int per = (nb + 1023) >> 10;
    int base = t * per;
    int s = 0;
    for (int j = 0; j < per; ++j) {
        int i = base + j;
        if (i < nb) s += bsum[i];
    }
    part[t] = s;
    __syncthreads();
    for (int o = 1; o < 1024; o <<= 1) {
        int v = 0;
        if (t >= o) v = part[t - o];
        __syncthreads();
        if (t >= o) part[t] += v;
        __syncthreads();
    }
    int run = (t > 0) ? part[t - 1] : 0;
    for (int j = 0; j < per; ++j) {
        int i = base + j;
        if (i < nb) { bofs[i] = run; run += bsum[i]; }
    }
    if (t == 1023) bofs[nb] = part[1023];
}

__global__ __launch_bounds__(256) void scanw_k(const int* __restrict__ cnt,
                                               const int* __restrict__ bofs,
                                               int* __restrict__ row_ptr, int nk) {
    __shared__ int sh[256];
    int t = threadIdx.x, idx = blockIdx.x * 256 + t;
    int v = (idx < nk) ? cnt[idx] : 0;
    sh[t] = v;
    __syncthreads();
    for (int o = 1; o < 256; o <<= 1) {
        int u = 0;
        if (t >= o) u = sh[t - o];
        __syncthreads();
        if (t >= o) sh[t] += u;
        __syncthreads();
    }
    if (idx < nk) row_ptr[idx] = bofs[blockIdx.x] + sh[t] - v;
    if (idx == nk - 1) row_ptr[nk] = bofs[blockIdx.x] + sh[t];
}

__global__ __launch_bounds__(256) void scatter_k(const int* __restrict__ src, const int* __restrict__ dst,
                                                 const int* __restrict__ row_ptr, int* __restrict__ fill,
                                                 int* __restrict__ col, int* __restrict__ dstc,
                                                 int E, int n) {
    int e = blockIdx.x * 256 + threadIdx.x;
    if (e < E + n) {
        int s, d;
        if (e < E) { s = src[e]; d = dst[e]; }
        else       { s = d = e - E; }
        int key = d * KPD + (s >> BLKSH);
        int pos = row_ptr[key] + atomicAdd(&fill[key], 1);
        col[pos] = s;
        dstc[pos] = d;
    }
}

// ---------------- input split (fp32 -> bf16 hi/lo), row+K padded -----------

__global__ __launch_bounds__(256) void xsplit_k(const float* __restrict__ in,
                                                u16* __restrict__ hi, u16* __restrict__ lo,
                                                int Nn, int K, int Kp, int Mp) {
    int idx = blockIdx.x * 256 + threadIdx.x;
    if (idx >= Mp * Kp) return;
    int m = idx / Kp, k = idx - m * Kp;
    float v = (m < Nn && k < K) ? in[(size_t)m * K + k] : 0.f;
    u16 h = f2bf(v);
    hi[idx] = h;
    lo[idx] = f2bf(v - bf2f(h));
}

// ---------------- all three W splits (transposed, padded) ------------------
// seg1 W1t: [512 x 160] @ 0 ; seg2 W2t: [384 x 448] @ 81920 ;
// seg3 W3t: [256 x 384] @ 253952 (total 352256)

__global__ __launch_bounds__(256) void wsplitAll_k(const float* __restrict__ W1,
                                                   const float* __restrict__ W2,
                                                   const float* __restrict__ W3,
                                                   u16* __restrict__ hi, u16* __restrict__ lo) {
    int idx = blockIdx.x * 256 + threadIdx.x;
    if (idx >= 352256) return;
    const float* W; int loc, Kp, K, N;
    if (idx < 81920)       { W = W1; loc = idx;          Kp = 160; K = 129; N = 448; }
    else if (idx < 253952) { W = W2; loc = idx - 81920;  Kp = 448; K = 448; N = 384; }
    else                   { W = W3; loc = idx - 253952; Kp = 384; K = 384; N = 240; }
    int nn = loc / Kp, k = loc - nn * Kp;
    float v = (k < K && nn < N) ? W[(size_t)k * N + nn] : 0.f;
    u16 h = f2bf(v);
    hi[idx] = h;
    lo[idx] = f2bf(v - bf2f(h));
}

// ---------------- projection tables P[k][h] ----------------
// P1 rows [0,160), P2 rows [160,608), P3 rows [608,992).

__global__ __launch_bounds__(256) void projAll_k(
    const float* __restrict__ W1, const float* __restrict__ a1s, const float* __restrict__ a1d,
    const float* __restrict__ W2, const float* __restrict__ a2s, const float* __restrict__ a2d,
    const float* __restrict__ W3, const float* __restrict__ a3s, const float* __restrict__ a3d,
    float* __restrict__ Ps, float* __restrict__ Pd) {
    int idx = blockIdx.x * 256 + threadIdx.x;
    if (idx >= 992 * 8) return;
    int row = idx >> 3, h = idx & 7;
    const float *W, *as_, *ad_; int k, K, Ncols, H, C;
    if (row < 160)      { k = row;       K = 129; W = W1; as_ = a1s; ad_ = a1d; Ncols = 448; H = 7; C = 64; }
    else if (row < 608) { k = row - 160; K = 448; W = W2; as_ = a2s; ad_ = a2d; Ncols = 384; H = 6; C = 64; }
    else                { k = row - 608; K = 384; W = W3; as_ = a3s; ad_ = a3d; Ncols = 240; H = 6; C = 40; }
    float ps = 0.f, pd = 0.f;
    if (h < H && k < K) {
        const float* wr = W + (size_t)k * Ncols + h * C;
        const float* ar = as_ + h * C;
        const float* dr = ad_ + h * C;
        for (int c = 0; c < C; ++c) {
            float wv = wr[c];
            ps += wv * ar[c];
            pd += wv * dr[c];
        }
    }
    Ps[idx] = ps;
    Pd[idx] = pd;
}

// ---------------- zero h1 split pad rows ----------------

__global__ __launch_bounds__(256) void zeropads_k(u16* __restrict__ h1hi, u16* __restrict__ h1lo,
                                                  int Nn) {
    int tot = (MPAD - Nn) * 448;
    int idx = blockIdx.x * 256 + threadIdx.x;
    if (idx < tot) {
        h1hi[(size_t)Nn * 448 + idx] = 0;
        h1lo[(size_t)Nn * 448 + idx] = 0;
    }
}

// ---------------- layer-1 alphas: (x @ P1) ----------------

__global__ __launch_bounds__(256) void alpha1_k(const float* __restrict__ x,
                                                const float* __restrict__ Ps,
                                                const float* __restrict__ Pd,
                                                float* __restrict__ oS, float* __restrict__ oD, int n) {
    int wv = threadIdx.x >> 6, lane = threadIdx.x & 63;
    int i = blockIdx.x * 4 + wv;
    if (i >= n) return;
    const float* row = x + (size_t)i * NFEAT;
    float x0 = row[lane], x1 = row[64 + lane];
    float ps[8], pd[8];
    #pragma unroll
    for (int h = 0; h < 8; ++h) {
        ps[h] = x0 * Ps[lane * 8 + h] + x1 * Ps[(64 + lane) * 8 + h];
        pd[h] = x0 * Pd[lane * 8 + h] + x1 * Pd[(64 + lane) * 8 + h];
    }
    if (lane == 0) {
        float x2 = row[128];
        #pragma unroll
        for (int h = 0; h < 8; ++h) {
            ps[h] += x2 * Ps[128 * 8 + h];
            pd[h] += x2 * Pd[128 * 8 + h];
        }
    }
    #pragma unroll
    for (int h = 0; h < 8; ++h) {
        #pragma unroll
        for (int off = 32; off; off >>= 1) {
            ps[h] += __shfl_xor(ps[h], off);
            pd[h] += __shfl_xor(pd[h], off);
        }
    }
    if (lane == 0) {
        #pragma unroll
        for (int h = 0; h < 8; ++h) {
            oS[(size_t)i * 8 + h] = ps[h];
            oD[(size_t)i * 8 + h] = pd[h];
        }
    }
}

// ---------------- alphas for layers 2/3 from split h ----------------

template <int KC>
__global__ __launch_bounds__(256) void alphaproj_k(const u16* __restrict__ Hhi,
                                                   const u16* __restrict__ Hlo,
                                                   const float* __restrict__ Ps,
                                                   const float* __restrict__ Pd,
                                                   float* __restrict__ oS, float* __restrict__ oD, int n) {
    constexpr int STRIDE = KC * 64;
    int wv = threadIdx.x >> 6, lane = threadIdx.x & 63;
    int i = blockIdx.x * 4 + wv;
    if (i >= n) return;
    const u16* bh = Hhi + (size_t)i * STRIDE;
    const u16* bl = Hlo + (size_t)i * STRIDE;
    float ps[8] = {}, pd[8] = {};
    #pragma unroll
    for (int kc = 0; kc < KC; ++kc) {
        int k = kc * 64 + lane;
        float v = bf2f(bh[k]) + bf2f(bl[k]);
        #pragma unroll
        for (int h = 0; h < 8; ++h) {
            ps[h] += v * Ps[k * 8 + h];
            pd[h] += v * Pd[k * 8 + h];
        }
    }
    #pragma unroll
    for (int h = 0; h < 8; ++h) {
        #pragma unroll
        for (int off = 32; off; off >>= 1) {
            ps[h] += __shfl_xor(ps[h], off);
            pd[h] += __shfl_xor(pd[h], off);
        }
    }
    if (lane == 0) {
        #pragma unroll
        for (int h = 0; h < 8; ++h) {
            oS[(size_t)i * 8 + h] = ps[h];
            oD[(size_t)i * 8 + h] = pd[h];
        }
    }
}

// ---------------- per-edge weights: w[e][h] = exp(lrelu(as[src]+ad[dst])) ---

__global__ __launch_bounds__(256) void edgew_k(const float* __restrict__ as_,
                                               const float* __restrict__ ad_,
                                               const int* __restrict__ col,
                                               const int* __restrict__ dstc,
                                               float* __restrict__ w, int Et) {
    int idx = blockIdx.x * 256 + threadIdx.x;
    if (idx >= Et * 8) return;
    int e = idx >> 3, h = idx & 7;
    int s = col[e], d = dstc[e];
    float v = as_[(size_t)s * 8 + h] + ad_[(size_t)d * 8 + h];
    v = v > 0.f ? v : 0.2f * v;
    w[idx] = __expf(v);
}

// ---------------- LDS swizzle helper ----------------

__device__ __forceinline__ int swz(int r, int s) {
    return (r << 2) | ((s ^ (r & 3) ^ ((r >> 2) & 3)) & 3);
}

// ---------------- split MFMA GEMM, fp32 output ----------------
// Tile 128x128, BK=32, 4 waves (2m x 2n), 3 MFMAs per hi/lo pair.

__global__ __launch_bounds__(256) void gemm32(
    const u16* __restrict__ Ahi, const u16* __restrict__ Alo,
    const u16* __restrict__ Bhi, const u16* __restrict__ Blo,
    float* __restrict__ C, int M, int Ncols, int Kp)
{
    __shared__ __align__(16) u16 sAh[128 * 32];
    __shared__ __align__(16) u16 sAl[128 * 32];
    __shared__ __align__(16) u16 sBh[128 * 32];
    __shared__ __align__(16) u16 sBl[128 * 32];
    const int tid = threadIdx.x;
    const int m0 = blockIdx.y * 128;
    const int n0 = blockIdx.x * 128;
    const int lane = tid & 63, wave = tid >> 6;
    const int wm = wave >> 1, wn = wave & 1;
    const int l15 = lane & 15, lg = lane >> 4;
    const int r0 = tid >> 2, s0 = tid & 3;
    const int w0 = swz(r0, s0), w1 = swz(r0 + 64, s0);
    f32x4 acc[4][4] = {};

    for (int k0 = 0; k0 < Kp; k0 += 32) {
        size_t gA0 = (size_t)(m0 + r0) * Kp + k0 + s0 * 8;
        size_t gA1 = (size_t)(m0 + r0 + 64) * Kp + k0 + s0 * 8;
        size_t gB0 = (size_t)(n0 + r0) * Kp + k0 + s0 * 8;
        size_t gB1 = (size_t)(n0 + r0 + 64) * Kp + k0 + s0 * 8;
        short8v ah0 = *(const short8v*)(Ahi + gA0);
        short8v ah1 = *(const short8v*)(Ahi + gA1);
        short8v al0 = *(const short8v*)(Alo + gA0);
        short8v al1 = *(const short8v*)(Alo + gA1);
        short8v bh0 = *(const short8v*)(Bhi + gB0);
        short8v bh1 = *(const short8v*)(Bhi + gB1);
        short8v bl0 = *(const short8v*)(Blo + gB0);
        short8v bl1 = *(const short8v*)(Blo + gB1);
        __syncthreads();
        ((short8v*)sAh)[w0] = ah0; ((short8v*)sAh)[w1] = ah1;
        ((short8v*)sAl)[w0] = al0; ((short8v*)sAl)[w1] = al1;
        ((short8v*)sBh)[w0] = bh0; ((short8v*)sBh)[w1] = bh1;
        ((short8v*)sBl)[w0] = bl0; ((short8v*)sBl)[w1] = bl1;
        __syncthreads();
        FragU fah[4], fal[4], fbh[4], fbl[4];
        #pragma unroll
        for (int mf = 0; mf < 4; ++mf) {
            int rr = wm * 64 + mf * 16 + l15;
            int idx = swz(rr, lg);
            fah[mf].s = ((const short8v*)sAh)[idx];
            fal[mf].s = ((const short8v*)sAl)[idx];
        }
        #pragma unroll
        for (int nf = 0; nf < 4; ++nf) {
            int rr = wn * 64 + nf * 16 + l15;
            int idx = swz(rr, lg);
            fbh[nf].s = ((const short8v*)sBh)[idx];
            fbl[nf].s = ((const short8v*)sBl)[idx];
        }
        #pragma unroll
        for (int mf = 0; mf < 4; ++mf) {
            #pragma unroll
            for (int nf = 0; nf < 4; ++nf) {
                acc[mf][nf] = __builtin_amdgcn_mfma_f32_16x16x32_bf16(fah[mf].b, fbh[nf].b, acc[mf][nf], 0, 0, 0);
                acc[mf][nf] = __builtin_amdgcn_mfma_f32_16x16x32_bf16(fah[mf].b, fbl[nf].b, acc[mf][nf], 0, 0, 0);
                acc[mf][nf] = __builtin_amdgcn_mfma_f32_16x16x32_bf16(fal[mf].b, fbh[nf].b, acc[mf][nf], 0, 0, 0);
            }
        }
    }
    #pragma unroll
    for (int mf = 0; mf < 4; ++mf) {
        #pragma unroll
        for (int nf = 0; nf < 4; ++nf) {
            int colg = n0 + wn * 64 + nf * 16 + l15;
            if (colg >= Ncols) continue;
            #pragma unroll
            for (int r = 0; r < 4; ++r) {
                int rowg = m0 + wm * 64 + mf * 16 + lg * 4 + r;
                if (rowg < M) C[(size_t)rowg * Ncols + colg] = acc[mf][nf][r];
            }
        }
    }
}

// ---------------- r5-structure agg: wave = (node, channel chunk) -----------
// fp32 hfeat, precomputed w stream, float4/lane, inline lead-lane denom.

template <int H, int C, int CPB, bool RELU, bool SPLIT>
__global__ __launch_bounds__(256) void gat_agg4(
    const float* __restrict__ hfeat, const float* __restrict__ w,
    const float* __restrict__ bias,
    const int* __restrict__ row_ptr, const int* __restrict__ col,
    float* __restrict__ outf, u16* __restrict__ ohi, u16* __restrict__ olo, int n)
{
    constexpr int HC = H * C;
    const int wv = threadIdx.x >> 6, lane = threadIdx.x & 63;
    const int i = blockIdx.x * 4 + wv;
    if (i >= n) return;
    const int ch = blockIdx.y * CPB + lane * 4;
    const bool act = (lane * 4 < CPB) && (ch < HC);
    const int h = act ? (ch / C) : 0;
    const int cinh = act ? (ch % C) : 0;
    const int beg = row_ptr[i * KPD], end = row_ptr[(i + 1) * KPD];
    float a0 = 0.f, a1 = 0.f, a2 = 0.f, a3 = 0.f, dp = 0.f;
    if (act) {
        const bool lead = (cinh == 0);
        int e = beg;
        for (; e + 2 <= end; e += 2) {
            int sA = col[e], sB = col[e + 1];
            float wA = w[(size_t)e * 8 + h];
            float wB = w[(size_t)(e + 1) * 8 + h];
            float4 hA = *(const float4*)(hfeat + (size_t)sA * HC + ch);
            float4 hB = *(const float4*)(hfeat + (size_t)sB * HC + ch);
            a0 += wA * hA.x + wB * hB.x;
            a1 += wA * hA.y + wB * hB.y;
            a2 += wA * hA.z + wB * hB.z;
            a3 += wA * hA.w + wB * hB.w;
            if (lead) dp += wA + wB;
        }
        if (e < end) {
            int sA = col[e];
            float wA = w[(size_t)e * 8 + h];
            float4 hA = *(const float4*)(hfeat + (size_t)sA * HC + ch);
            a0 += wA * hA.x; a1 += wA * hA.y; a2 += wA * hA.z; a3 += wA * hA.w;
            if (lead) dp += wA;
        }
    }
    const float den = __shfl(dp, lane - (cinh >> 2)) + 1e-16f;
    if (act) {
        const float4 b4 = *(const float4*)(bias + ch);
        float o0 = a0 / den + b4.x;
        float o1 = a1 / den + b4.y;
        float o2 = a2 / den + b4.z;
        float o3 = a3 / den + b4.w;
        if (RELU) {
            o0 = fmaxf(o0, 0.f); o1 = fmaxf(o1, 0.f);
            o2 = fmaxf(o2, 0.f); o3 = fmaxf(o3, 0.f);
        }
        size_t base = (size_t)i * HC + ch;
        if constexpr (SPLIT) {
            ushort4 ph, pl;
            ph.x = f2bf(o0); pl.x = f2bf(o0 - bf2f(ph.x));
            ph.y = f2bf(o1); pl.y = f2bf(o1 - bf2f(ph.y));
            ph.z = f2bf(o2); pl.z = f2bf(o2 - bf2f(ph.z));
            ph.w = f2bf(o3); pl.w = f2bf(o3 - bf2f(ph.w));
            *(ushort4*)(ohi + base) = ph;
            *(ushort4*)(olo + base) = pl;
        } else {
            float4 o; o.x = o0; o.y = o1; o.z = o2; o.w = o3;
            *(float4*)(outf + base) = o;
        }
    }
}

// ---------------------------------------------------------------------------

extern "C" void kernel_launch(void* const* d_in, const int* in_sizes, int n_in,
                              void* d_out, int out_size, void* d_ws, size_t ws_size,
                              hipStream_t stream) {
    const float* x   = (const float*)d_in[0];
    const int*   ei  = (const int*)d_in[1];
    const float* W1  = (const float*)d_in[2];
    const float* a1s = (const float*)d_in[3];
    const float* a1d = (const float*)d_in[4];
    const float* b1  = (const float*)d_in[5];
    const float* W2  = (const float*)d_in[6];
    const float* a2s = (const float*)d_in[7];
    const float* a2d = (const float*)d_in[8];
    const float* b2  = (const float*)d_in[9];
    const float* W3  = (const float*)d_in[10];
    const float* a3s = (const float*)d_in[11];
    const float* a3d = (const float*)d_in[12];
    const float* b3  = (const float*)d_in[13];
    float* out = (float*)d_out;

    const int Nn = in_sizes[0] / NFEAT;   // 30000
    const int E  = in_sizes[1] / 2;       // 480000
    const int Et = E + Nn;
    const int NK = Nn * KPD;
    const int NB = (NK + 255) / 256;
    const int* srcp = ei;
    const int* dstp = ei + E;

    char* ws = (char*)d_ws;
    size_t off = 0;
    auto carve = [&](size_t bytes) -> char* {
        char* p = ws + off;
        off += (bytes + 255) & ~(size_t)255;
        return p;
    };
    float* hbuf  = (float*)carve((size_t)MPAD * 448 * 4);  // fp32 h~ (all layers)
    u16*   h1hi  = (u16*)carve((size_t)MPAD * 448 * 2);    // h split
    u16*   h1lo  = (u16*)carve((size_t)MPAD * 448 * 2);
    u16*   Xhi   = (u16*)carve((size_t)MPAD * 160 * 2);
    u16*   Xlo   = (u16*)carve((size_t)MPAD * 160 * 2);
    u16*   Wthi  = (u16*)carve((size_t)352256 * 2);
    u16*   Wtlo  = (u16*)carve((size_t)352256 * 2);
    float* wbuf  = (float*)carve((size_t)Et * 8 * 4);
    int*   col   = (int*)carve((size_t)Et * 4);
    int*   dstc  = (int*)carve((size_t)Et * 4);
    int* row_ptr = (int*)carve((size_t)(NK + 1) * 4);
    int*   cnt   = (int*)carve((size_t)NK * 4);
    int*   bsum  = (int*)carve((size_t)NB * 4);
    int*   bofs  = (int*)carve((size_t)(NB + 1) * 4);
    float* aA    = (float*)carve((size_t)Nn * 8 * 4);
    float* dA    = (float*)carve((size_t)Nn * 8 * 4);
    float* aB    = (float*)carve((size_t)Nn * 8 * 4);
    float* dB    = (float*)carve((size_t)Nn * 8 * 4);
    float* Ps    = (float*)carve((size_t)992 * 8 * 4);
    float* Pd    = (float*)carve((size_t)992 * 8 * 4);
    (void)ws_size;

    const int nb4 = (Nn + 3) / 4;   // 7500
    const int mg  = MPAD / 128;     // 235

    // ---- CSR keyed by (dst, src-block) ----
    hipMemsetAsync(cnt, 0, (size_t)NK * 4, stream);
    hist_k<<<(Et + 255) / 256, 256, 0, stream>>>(srcp, dstp, cnt, E, Nn);
    bsum_k<<<NB, 256, 0, stream>>>(cnt, bsum, NK);
    bscan_k<<<1, 1024, 0, stream>>>(bsum, bofs, NB);
    scanw_k<<<NB, 256, 0, stream>>>(cnt, bofs, row_ptr, NK);
    hipMemsetAsync(cnt, 0, (size_t)NK * 4, stream);
    scatter_k<<<(Et + 255) / 256, 256, 0, stream>>>(srcp, dstp, row_ptr, cnt, col, dstc, E, Nn);

    // ---- input prep ----
    xsplit_k<<<((MPAD * 160) + 255) / 256, 256, 0, stream>>>(x, Xhi, Xlo, Nn, NFEAT, 160, MPAD);
    wsplitAll_k<<<(352256 + 255) / 256, 256, 0, stream>>>(W1, W2, W3, Wthi, Wtlo);
    projAll_k<<<(992 * 8 + 255) / 256, 256, 0, stream>>>(W1, a1s, a1d, W2, a2s, a2d, W3, a3s, a3d, Ps, Pd);
    zeropads_k<<<(((MPAD - Nn) * 448) + 255) / 256, 256, 0, stream>>>(h1hi, h1lo, Nn);

    // ---- layer 1: x(129) -> 7x64  (HC=448, chunks {256,192}) ----
    alpha1_k<<<nb4, 256, 0, stream>>>(x, Ps, Pd, aA, dA, Nn);
    edgew_k<<<(Et * 8 + 255) / 256, 256, 0, stream>>>(aA, dA, col, dstc, wbuf, Et);
    gemm32<<<dim3(4, mg), 256, 0, stream>>>(Xhi, Xlo, Wthi, Wtlo, hbuf, Nn, 448, 160);
    gat_agg4<7, 64, 256, true, true><<<dim3(nb4, 2), 256, 0, stream>>>(
        hbuf, wbuf, b1, row_ptr, col, nullptr, h1hi, h1lo, Nn);
    alphaproj_k<7><<<nb4, 256, 0, stream>>>(h1hi, h1lo, Ps + 1280, Pd + 1280, aB, dB, Nn);

    // ---- layer 2: 448 -> 6x64  (HC=384, chunks {192,192}) ----
    edgew_k<<<(Et * 8 + 255) / 256, 256, 0, stream>>>(aB, dB, col, dstc, wbuf, Et);
    gemm32<<<dim3(3, mg), 256, 0, stream>>>(h1hi, h1lo, Wthi + 81920, Wtlo + 81920, hbuf, Nn, 384, 448);
    gat_agg4<6, 64, 192, true, true><<<dim3(nb4, 2), 256, 0, stream>>>(
        hbuf, wbuf, b2, row_ptr, col, nullptr, h1hi, h1lo, Nn);
    alphaproj_k<6><<<nb4, 256, 0, stream>>>(h1hi, h1lo, Ps + 4864, Pd + 4864, aA, dA, Nn);

    // ---- layer 3: 384 -> 6x40  (HC=240, single chunk) ----
    edgew_k<<<(Et * 8 + 255) / 256, 256, 0, stream>>>(aA, dA, col, dstc, wbuf, Et);
    gemm32<<<dim3(2, mg), 256, 0, stream>>>(h1hi, h1lo, Wthi + 253952, Wtlo + 253952, hbuf, Nn, 240, 384);
    gat_agg4<6, 40, 240, false, false><<<dim3(nb4, 1), 256, 0, stream>>>(
        hbuf, wbuf, b3, row_ptr, col, out, nullptr, nullptr, Nn);
}

// Round 13
// 507.003 us; speedup vs baseline: 1.2511x; 1.2511x over previous
//
#include <hip/hip_runtime.h>
#include <hip/hip_bf16.h>

// ---------------------------------------------------------------------------
// 3-layer GAT forward (PyG GATConv, eval) on MI355X.
// Agg (aggL_k) = r5/r12's measured-best LOOP STRUCTURE (streaming e-indexed
// precomputed weights, single dependent gather, lean ~28 VGPR body, inline
// lead-lane denominators) applied to the HALF-SIZE fp16 h~ table (8ch/lane).
// GEMM: split-bf16 MFMA (3 products ~ fp32 accuracy), fp16 h~ output +
// split-bf16 h for the next GEMM. Alphas via x@(W@a) / h@(W@a) identity.
// CSR: (dst, src-block)-keyed histogram + 3-stage hierarchical scan.
// ---------------------------------------------------------------------------

#define NFEAT 129
#define MPAD  30080   // 235 * 128
#define BLKSH 11
#define KPD   16

typedef __attribute__((ext_vector_type(8))) short short8v;
typedef __attribute__((ext_vector_type(8))) unsigned short u16x8;
typedef __attribute__((ext_vector_type(8))) __bf16 bf16x8;
typedef __attribute__((ext_vector_type(4))) float f32x4;
typedef unsigned short u16;

union FragU { short8v s; bf16x8 b; };

__device__ inline u16 f2bf(float x) {
    unsigned u = __builtin_bit_cast(unsigned, x);
    unsigned r = (u + 0x7fffu + ((u >> 16) & 1u)) >> 16;
    return (u16)r;
}
__device__ inline float bf2f(u16 b) {
    unsigned u = ((unsigned)b) << 16;
    return __builtin_bit_cast(float, u);
}
__device__ inline float h2f(u16 u) { return (float)__builtin_bit_cast(_Float16, u); }
__device__ inline u16 f2h(float v) { return __builtin_bit_cast(u16, (_Float16)v); }

// ---------------- CSR build (keyed by dst*KPD + src-block) ----------------

__global__ __launch_bounds__(256) void hist_k(const int* __restrict__ src,
                                              const int* __restrict__ dst,
                                              int* __restrict__ cnt, int E, int n) {
    int e = blockIdx.x * 256 + threadIdx.x;
    if (e < E + n) {
        int s, d;
        if (e < E) { s = src[e]; d = dst[e]; }
        else       { s = d = e - E; }
        atomicAdd(&cnt[d * KPD + (s >> BLKSH)], 1);
    }
}

__global__ __launch_bounds__(256) void bsum_k(const int* __restrict__ cnt,
                                              int* __restrict__ bsum, int nk) {
    __shared__ int sh[256];
    int t = threadIdx.x, idx = blockIdx.x * 256 + t;
    sh[t] = (idx < nk) ? cnt[idx] : 0;
    __syncthreads();
    for (int o = 128; o; o >>= 1) {
        if (t < o) sh[t] += sh[t + o];
        __syncthreads();
    }
    if (t == 0) bsum[blockIdx.x] = sh[0];
}

__global__ __launch_bounds__(1024) void bscan_k(const int* __restrict__ bsum,
                                                int* __restrict__ bofs, int nb) {
    __shared__ int part[1024];
    int t = threadIdx.x;
    int per = (nb + 1023) >> 10;
    int base = t * per;
    int s = 0;
    for (int j = 0; j < per; ++j) {
        int i = base + j;
        if (i < nb) s += bsum[i];
    }
    part[t] = s;
    __syncthreads();
    for (int o = 1; o < 1024; o <<= 1) {
        int v = 0;
        if (t >= o) v = part[t - o];
        __syncthreads();
        if (t >= o) part[t] += v;
        __syncthreads();
    }
    int run = (t > 0) ? part[t - 1] : 0;
    for (int j = 0; j < per; ++j) {
        int i = base + j;
        if (i < nb) { bofs[i] = run; run += bsum[i]; }
    }
    if (t == 1023) bofs[nb] = part[1023];
}

__global__ __launch_bounds__(256) void scanw_k(const int* __restrict__ cnt,
                                               const int* __restrict__ bofs,
                                               int* __restrict__ row_ptr, int nk) {
    __shared__ int sh[256];
    int t = threadIdx.x, idx = blockIdx.x * 256 + t;
    int v = (idx < nk) ? cnt[idx] : 0;
    sh[t] = v;
    __syncthreads();
    for (int o = 1; o < 256; o <<= 1) {
        int u = 0;
        if (t >= o) u = sh[t - o];
        __syncthreads();
        if (t >= o) sh[t] += u;
        __syncthreads();
    }
    if (idx < nk) row_ptr[idx] = bofs[blockIdx.x] + sh[t] - v;
    if (idx == nk - 1) row_ptr[nk] = bofs[blockIdx.x] + sh[t];
}

__global__ __launch_bounds__(256) void scatter_k(const int* __restrict__ src, const int* __restrict__ dst,
                                                 const int* __restrict__ row_ptr, int* __restrict__ fill,
                                                 int* __restrict__ col, int* __restrict__ dstc,
                                                 int E, int n) {
    int e = blockIdx.x * 256 + threadIdx.x;
    if (e < E + n) {
        int s, d;
        if (e < E) { s = src[e]; d = dst[e]; }
        else       { s = d = e - E; }
        int key = d * KPD + (s >> BLKSH);
        int pos = row_ptr[key] + atomicAdd(&fill[key], 1);
        col[pos] = s;
        dstc[pos] = d;
    }
}

// ---------------- input split (fp32 -> bf16 hi/lo), row+K padded -----------

__global__ __launch_bounds__(256) void xsplit_k(const float* __restrict__ in,
                                                u16* __restrict__ hi, u16* __restrict__ lo,
                                                int Nn, int K, int Kp, int Mp) {
    int idx = blockIdx.x * 256 + threadIdx.x;
    if (idx >= Mp * Kp) return;
    int m = idx / Kp, k = idx - m * Kp;
    float v = (m < Nn && k < K) ? in[(size_t)m * K + k] : 0.f;
    u16 h = f2bf(v);
    hi[idx] = h;
    lo[idx] = f2bf(v - bf2f(h));
}

// ---------------- all three W splits (transposed, padded) ------------------
// seg1 W1t: [512 x 160] @ 0 ; seg2 W2t: [384 x 448] @ 81920 ;
// seg3 W3t: [256 x 384] @ 253952 (total 352256)

__global__ __launch_bounds__(256) void wsplitAll_k(const float* __restrict__ W1,
                                                   const float* __restrict__ W2,
                                                   const float* __restrict__ W3,
                                                   u16* __restrict__ hi, u16* __restrict__ lo) {
    int idx = blockIdx.x * 256 + threadIdx.x;
    if (idx >= 352256) return;
    const float* W; int loc, Kp, K, N;
    if (idx < 81920)       { W = W1; loc = idx;          Kp = 160; K = 129; N = 448; }
    else if (idx < 253952) { W = W2; loc = idx - 81920;  Kp = 448; K = 448; N = 384; }
    else                   { W = W3; loc = idx - 253952; Kp = 384; K = 384; N = 240; }
    int nn = loc / Kp, k = loc - nn * Kp;
    float v = (k < K && nn < N) ? W[(size_t)k * N + nn] : 0.f;
    u16 h = f2bf(v);
    hi[idx] = h;
    lo[idx] = f2bf(v - bf2f(h));
}

// ---------------- projection tables P[k][h] ----------------
// P1 rows [0,160), P2 rows [160,608), P3 rows [608,992).

__global__ __launch_bounds__(256) void projAll_k(
    const float* __restrict__ W1, const float* __restrict__ a1s, const float* __restrict__ a1d,
    const float* __restrict__ W2, const float* __restrict__ a2s, const float* __restrict__ a2d,
    const float* __restrict__ W3, const float* __restrict__ a3s, const float* __restrict__ a3d,
    float* __restrict__ Ps, float* __restrict__ Pd) {
    int idx = blockIdx.x * 256 + threadIdx.x;
    if (idx >= 992 * 8) return;
    int row = idx >> 3, h = idx & 7;
    const float *W, *as_, *ad_; int k, K, Ncols, H, C;
    if (row < 160)      { k = row;       K = 129; W = W1; as_ = a1s; ad_ = a1d; Ncols = 448; H = 7; C = 64; }
    else if (row < 608) { k = row - 160; K = 448; W = W2; as_ = a2s; ad_ = a2d; Ncols = 384; H = 6; C = 64; }
    else                { k = row - 608; K = 384; W = W3; as_ = a3s; ad_ = a3d; Ncols = 240; H = 6; C = 40; }
    float ps = 0.f, pd = 0.f;
    if (h < H && k < K) {
        const float* wr = W + (size_t)k * Ncols + h * C;
        const float* ar = as_ + h * C;
        const float* dr = ad_ + h * C;
        for (int c = 0; c < C; ++c) {
            float wv = wr[c];
            ps += wv * ar[c];
            pd += wv * dr[c];
        }
    }
    Ps[idx] = ps;
    Pd[idx] = pd;
}

// ---------------- zero h1 split pad rows ----------------

__global__ __launch_bounds__(256) void zeropads_k(u16* __restrict__ h1hi, u16* __restrict__ h1lo,
                                                  int Nn) {
    int tot = (MPAD - Nn) * 448;
    int idx = blockIdx.x * 256 + threadIdx.x;
    if (idx < tot) {
        h1hi[(size_t)Nn * 448 + idx] = 0;
        h1lo[(size_t)Nn * 448 + idx] = 0;
    }
}

// ---------------- layer-1 alphas: (x @ P1) ----------------

__global__ __launch_bounds__(256) void alpha1_k(const float* __restrict__ x,
                                                const float* __restrict__ Ps,
                                                const float* __restrict__ Pd,
                                                float* __restrict__ oS, float* __restrict__ oD, int n) {
    int wv = threadIdx.x >> 6, lane = threadIdx.x & 63;
    int i = blockIdx.x * 4 + wv;
    if (i >= n) return;
    const float* row = x + (size_t)i * NFEAT;
    float x0 = row[lane], x1 = row[64 + lane];
    float ps[8], pd[8];
    #pragma unroll
    for (int h = 0; h < 8; ++h) {
        ps[h] = x0 * Ps[lane * 8 + h] + x1 * Ps[(64 + lane) * 8 + h];
        pd[h] = x0 * Pd[lane * 8 + h] + x1 * Pd[(64 + lane) * 8 + h];
    }
    if (lane == 0) {
        float x2 = row[128];
        #pragma unroll
        for (int h = 0; h < 8; ++h) {
            ps[h] += x2 * Ps[128 * 8 + h];
            pd[h] += x2 * Pd[128 * 8 + h];
        }
    }
    #pragma unroll
    for (int h = 0; h < 8; ++h) {
        #pragma unroll
        for (int off = 32; off; off >>= 1) {
            ps[h] += __shfl_xor(ps[h], off);
            pd[h] += __shfl_xor(pd[h], off);
        }
    }
    if (lane == 0) {
        #pragma unroll
        for (int h = 0; h < 8; ++h) {
            oS[(size_t)i * 8 + h] = ps[h];
            oD[(size_t)i * 8 + h] = pd[h];
        }
    }
}

// ---------------- alphas for layers 2/3 from split h ----------------

template <int KC>
__global__ __launch_bounds__(256) void alphaproj_k(const u16* __restrict__ Hhi,
                                                   const u16* __restrict__ Hlo,
                                                   const float* __restrict__ Ps,
                                                   const float* __restrict__ Pd,
                                                   float* __restrict__ oS, float* __restrict__ oD, int n) {
    constexpr int STRIDE = KC * 64;
    int wv = threadIdx.x >> 6, lane = threadIdx.x & 63;
    int i = blockIdx.x * 4 + wv;
    if (i >= n) return;
    const u16* bh = Hhi + (size_t)i * STRIDE;
    const u16* bl = Hlo + (size_t)i * STRIDE;
    float ps[8] = {}, pd[8] = {};
    #pragma unroll
    for (int kc = 0; kc < KC; ++kc) {
        int k = kc * 64 + lane;
        float v = bf2f(bh[k]) + bf2f(bl[k]);
        #pragma unroll
        for (int h = 0; h < 8; ++h) {
            ps[h] += v * Ps[k * 8 + h];
            pd[h] += v * Pd[k * 8 + h];
        }
    }
    #pragma unroll
    for (int h = 0; h < 8; ++h) {
        #pragma unroll
        for (int off = 32; off; off >>= 1) {
            ps[h] += __shfl_xor(ps[h], off);
            pd[h] += __shfl_xor(pd[h], off);
        }
    }
    if (lane == 0) {
        #pragma unroll
        for (int h = 0; h < 8; ++h) {
            oS[(size_t)i * 8 + h] = ps[h];
            oD[(size_t)i * 8 + h] = pd[h];
        }
    }
}

// ---------------- per-edge weights: w[e][h] = exp(lrelu(as[src]+ad[dst])) ---

__global__ __launch_bounds__(256) void edgew_k(const float* __restrict__ as_,
                                               const float* __restrict__ ad_,
                                               const int* __restrict__ col,
                                               const int* __restrict__ dstc,
                                               float* __restrict__ w, int Et) {
    int idx = blockIdx.x * 256 + threadIdx.x;
    if (idx >= Et * 8) return;
    int e = idx >> 3, h = idx & 7;
    int s = col[e], d = dstc[e];
    float v = as_[(size_t)s * 8 + h] + ad_[(size_t)d * 8 + h];
    v = v > 0.f ? v : 0.2f * v;
    w[idx] = __expf(v);
}

// ---------------- LDS swizzle helper ----------------

__device__ __forceinline__ int swz(int r, int s) {
    return (r << 2) | ((s ^ (r & 3) ^ ((r >> 2) & 3)) & 3);
}

// ---------------- split MFMA GEMM, fp16 output ----------------
// Tile 128x128, BK=32, 4 waves (2m x 2n), 3 MFMAs per hi/lo pair.

__global__ __launch_bounds__(256) void gemm16(
    const u16* __restrict__ Ahi, const u16* __restrict__ Alo,
    const u16* __restrict__ Bhi, const u16* __restrict__ Blo,
    u16* __restrict__ C16, int M, int Ncols, int Kp)
{
    __shared__ __align__(16) u16 sAh[128 * 32];
    __shared__ __align__(16) u16 sAl[128 * 32];
    __shared__ __align__(16) u16 sBh[128 * 32];
    __shared__ __align__(16) u16 sBl[128 * 32];
    const int tid = threadIdx.x;
    const int m0 = blockIdx.y * 128;
    const int n0 = blockIdx.x * 128;
    const int lane = tid & 63, wave = tid >> 6;
    const int wm = wave >> 1, wn = wave & 1;
    const int l15 = lane & 15, lg = lane >> 4;
    const int r0 = tid >> 2, s0 = tid & 3;
    const int w0 = swz(r0, s0), w1 = swz(r0 + 64, s0);
    f32x4 acc[4][4] = {};

    for (int k0 = 0; k0 < Kp; k0 += 32) {
        size_t gA0 = (size_t)(m0 + r0) * Kp + k0 + s0 * 8;
        size_t gA1 = (size_t)(m0 + r0 + 64) * Kp + k0 + s0 * 8;
        size_t gB0 = (size_t)(n0 + r0) * Kp + k0 + s0 * 8;
        size_t gB1 = (size_t)(n0 + r0 + 64) * Kp + k0 + s0 * 8;
        short8v ah0 = *(const short8v*)(Ahi + gA0);
        short8v ah1 = *(const short8v*)(Ahi + gA1);
        short8v al0 = *(const short8v*)(Alo + gA0);
        short8v al1 = *(const short8v*)(Alo + gA1);
        short8v bh0 = *(const short8v*)(Bhi + gB0);
        short8v bh1 = *(const short8v*)(Bhi + gB1);
        short8v bl0 = *(const short8v*)(Blo + gB0);
        short8v bl1 = *(const short8v*)(Blo + gB1);
        __syncthreads();
        ((short8v*)sAh)[w0] = ah0; ((short8v*)sAh)[w1] = ah1;
        ((short8v*)sAl)[w0] = al0; ((short8v*)sAl)[w1] = al1;
        ((short8v*)sBh)[w0] = bh0; ((short8v*)sBh)[w1] = bh1;
        ((short8v*)sBl)[w0] = bl0; ((short8v*)sBl)[w1] = bl1;
        __syncthreads();
        FragU fah[4], fal[4], fbh[4], fbl[4];
        #pragma unroll
        for (int mf = 0; mf < 4; ++mf) {
            int rr = wm * 64 + mf * 16 + l15;
            int idx = swz(rr, lg);
            fah[mf].s = ((const short8v*)sAh)[idx];
            fal[mf].s = ((const short8v*)sAl)[idx];
        }
        #pragma unroll
        for (int nf = 0; nf < 4; ++nf) {
            int rr = wn * 64 + nf * 16 + l15;
            int idx = swz(rr, lg);
            fbh[nf].s = ((const short8v*)sBh)[idx];
            fbl[nf].s = ((const short8v*)sBl)[idx];
        }
        #pragma unroll
        for (int mf = 0; mf < 4; ++mf) {
            #pragma unroll
            for (int nf = 0; nf < 4; ++nf) {
                acc[mf][nf] = __builtin_amdgcn_mfma_f32_16x16x32_bf16(fah[mf].b, fbh[nf].b, acc[mf][nf], 0, 0, 0);
                acc[mf][nf] = __builtin_amdgcn_mfma_f32_16x16x32_bf16(fah[mf].b, fbl[nf].b, acc[mf][nf], 0, 0, 0);
                acc[mf][nf] = __builtin_amdgcn_mfma_f32_16x16x32_bf16(fal[mf].b, fbh[nf].b, acc[mf][nf], 0, 0, 0);
            }
        }
    }
    #pragma unroll
    for (int mf = 0; mf < 4; ++mf) {
        #pragma unroll
        for (int nf = 0; nf < 4; ++nf) {
            int colg = n0 + wn * 64 + nf * 16 + l15;
            if (colg >= Ncols) continue;
            #pragma unroll
            for (int r = 0; r < 4; ++r) {
                int rowg = m0 + wm * 64 + mf * 16 + lg * 4 + r;
                if (rowg < M) C16[(size_t)rowg * Ncols + colg] = f2h(acc[mf][nf][r]);
            }
        }
    }
}

// ---------------- lean agg: fp16 table + streaming weights ----------------
// wave per node; lane owns 8 consecutive fp16 channels (16B load/edge).
// Single dependent load level (col -> hf); w[e*8+h] is an e-indexed stream.
// No PROJ, no inline exp: minimal VGPR for max resident waves.

template <int H, int C, bool RELU, bool SPLIT>
__global__ __launch_bounds__(256) void aggL_k(
    const u16* __restrict__ hf, const float* __restrict__ w,
    const float* __restrict__ bias,
    const int* __restrict__ row_ptr, const int* __restrict__ col,
    float* __restrict__ outf, u16* __restrict__ ohi, u16* __restrict__ olo, int n)
{
    constexpr int HC = H * C;
    constexpr int LACT = HC / 8;
    const int wv = threadIdx.x >> 6, lane = threadIdx.x & 63;
    const int i = blockIdx.x * 4 + wv;
    if (i >= n) return;
    const int ch0 = lane * 8;
    const bool act = lane < LACT;
    const int h = act ? (ch0 / C) : 0;
    const bool lead = act && ((ch0 % C) == 0);
    const int beg = row_ptr[i * KPD], end = row_ptr[(i + 1) * KPD];
    float acc[8] = {};
    float dp = 0.f;
    if (act) {
        int e = beg;
        for (; e + 2 <= end; e += 2) {
            int sA = col[e], sB = col[e + 1];
            float wA = w[(size_t)e * 8 + h];
            float wB = w[(size_t)(e + 1) * 8 + h];
            u16x8 vA = *(const u16x8*)(hf + (size_t)sA * HC + ch0);
            u16x8 vB = *(const u16x8*)(hf + (size_t)sB * HC + ch0);
            #pragma unroll
            for (int j = 0; j < 8; ++j)
                acc[j] += wA * h2f(vA[j]) + wB * h2f(vB[j]);
            if (lead) dp += wA + wB;
        }
        if (e < end) {
            int sA = col[e];
            float wA = w[(size_t)e * 8 + h];
            u16x8 vA = *(const u16x8*)(hf + (size_t)sA * HC + ch0);
            #pragma unroll
            for (int j = 0; j < 8; ++j)
                acc[j] += wA * h2f(vA[j]);
            if (lead) dp += wA;
        }
    }
    const float den = __shfl(dp, h * (C / 8)) + 1e-16f;
    if (act) {
        float o[8];
        #pragma unroll
        for (int j = 0; j < 8; ++j) {
            float v = acc[j] / den + bias[ch0 + j];
            if (RELU) v = fmaxf(v, 0.f);
            o[j] = v;
        }
        size_t base = (size_t)i * HC + ch0;
        if constexpr (SPLIT) {
            u16x8 ph, pl;
            #pragma unroll
            for (int j = 0; j < 8; ++j) {
                u16 hi = f2bf(o[j]);
                ph[j] = hi;
                pl[j] = f2bf(o[j] - bf2f(hi));
            }
            *(u16x8*)(ohi + base) = ph;
            *(u16x8*)(olo + base) = pl;
        } else {
            float4 q0; q0.x = o[0]; q0.y = o[1]; q0.z = o[2]; q0.w = o[3];
            float4 q1; q1.x = o[4]; q1.y = o[5]; q1.z = o[6]; q1.w = o[7];
            *(float4*)(outf + base) = q0;
            *(float4*)(outf + base + 4) = q1;
        }
    }
}

// ---------------------------------------------------------------------------

extern "C" void kernel_launch(void* const* d_in, const int* in_sizes, int n_in,
                              void* d_out, int out_size, void* d_ws, size_t ws_size,
                              hipStream_t stream) {
    const float* x   = (const float*)d_in[0];
    const int*   ei  = (const int*)d_in[1];
    const float* W1  = (const float*)d_in[2];
    const float* a1s = (const float*)d_in[3];
    const float* a1d = (const float*)d_in[4];
    const float* b1  = (const float*)d_in[5];
    const float* W2  = (const float*)d_in[6];
    const float* a2s = (const float*)d_in[7];
    const float* a2d = (const float*)d_in[8];
    const float* b2  = (const float*)d_in[9];
    const float* W3  = (const float*)d_in[10];
    const float* a3s = (const float*)d_in[11];
    const float* a3d = (const float*)d_in[12];
    const float* b3  = (const float*)d_in[13];
    float* out = (float*)d_out;

    const int Nn = in_sizes[0] / NFEAT;   // 30000
    const int E  = in_sizes[1] / 2;       // 480000
    const int Et = E + Nn;
    const int NK = Nn * KPD;
    const int NB = (NK + 255) / 256;
    const int* srcp = ei;
    const int* dstp = ei + E;

    char* ws = (char*)d_ws;
    size_t off = 0;
    auto carve = [&](size_t bytes) -> char* {
        char* p = ws + off;
        off += (bytes + 255) & ~(size_t)255;
        return p;
    };
    u16*   hbuf16 = (u16*)carve((size_t)MPAD * 448 * 2);   // fp16 h~ (all layers)
    u16*   h1hi  = (u16*)carve((size_t)MPAD * 448 * 2);    // h split
    u16*   h1lo  = (u16*)carve((size_t)MPAD * 448 * 2);
    u16*   Xhi   = (u16*)carve((size_t)MPAD * 160 * 2);
    u16*   Xlo   = (u16*)carve((size_t)MPAD * 160 * 2);
    u16*   Wthi  = (u16*)carve((size_t)352256 * 2);
    u16*   Wtlo  = (u16*)carve((size_t)352256 * 2);
    float* wbuf  = (float*)carve((size_t)Et * 8 * 4);
    int*   col   = (int*)carve((size_t)Et * 4);
    int*   dstc  = (int*)carve((size_t)Et * 4);
    int* row_ptr = (int*)carve((size_t)(NK + 1) * 4);
    int*   cnt   = (int*)carve((size_t)NK * 4);
    int*   bsum  = (int*)carve((size_t)NB * 4);
    int*   bofs  = (int*)carve((size_t)(NB + 1) * 4);
    float* aA    = (float*)carve((size_t)Nn * 8 * 4);
    float* dA    = (float*)carve((size_t)Nn * 8 * 4);
    float* aB    = (float*)carve((size_t)Nn * 8 * 4);
    float* dB    = (float*)carve((size_t)Nn * 8 * 4);
    float* Ps    = (float*)carve((size_t)992 * 8 * 4);
    float* Pd    = (float*)carve((size_t)992 * 8 * 4);
    (void)ws_size;

    const int nb4 = (Nn + 3) / 4;   // 7500
    const int mg  = MPAD / 128;     // 235

    // ---- CSR keyed by (dst, src-block) ----
    hipMemsetAsync(cnt, 0, (size_t)NK * 4, stream);
    hist_k<<<(Et + 255) / 256, 256, 0, stream>>>(srcp, dstp, cnt, E, Nn);
    bsum_k<<<NB, 256, 0, stream>>>(cnt, bsum, NK);
    bscan_k<<<1, 1024, 0, stream>>>(bsum, bofs, NB);
    scanw_k<<<NB, 256, 0, stream>>>(cnt, bofs, row_ptr, NK);
    hipMemsetAsync(cnt, 0, (size_t)NK * 4, stream);
    scatter_k<<<(Et + 255) / 256, 256, 0, stream>>>(srcp, dstp, row_ptr, cnt, col, dstc, E, Nn);

    // ---- input prep ----
    xsplit_k<<<((MPAD * 160) + 255) / 256, 256, 0, stream>>>(x, Xhi, Xlo, Nn, NFEAT, 160, MPAD);
    wsplitAll_k<<<(352256 + 255) / 256, 256, 0, stream>>>(W1, W2, W3, Wthi, Wtlo);
    projAll_k<<<(992 * 8 + 255) / 256, 256, 0, stream>>>(W1, a1s, a1d, W2, a2s, a2d, W3, a3s, a3d, Ps, Pd);
    zeropads_k<<<(((MPAD - Nn) * 448) + 255) / 256, 256, 0, stream>>>(h1hi, h1lo, Nn);

    // ---- layer 1: x(129) -> 7x64 ----
    alpha1_k<<<nb4, 256, 0, stream>>>(x, Ps, Pd, aA, dA, Nn);
    edgew_k<<<(Et * 8 + 255) / 256, 256, 0, stream>>>(aA, dA, col, dstc, wbuf, Et);
    gemm16<<<dim3(4, mg), 256, 0, stream>>>(Xhi, Xlo, Wthi, Wtlo, hbuf16, Nn, 448, 160);
    aggL_k<7, 64, true, true><<<nb4, 256, 0, stream>>>(
        hbuf16, wbuf, b1, row_ptr, col, nullptr, h1hi, h1lo, Nn);
    alphaproj_k<7><<<nb4, 256, 0, stream>>>(h1hi, h1lo, Ps + 1280, Pd + 1280, aB, dB, Nn);

    // ---- layer 2: 448 -> 6x64 ----
    edgew_k<<<(Et * 8 + 255) / 256, 256, 0, stream>>>(aB, dB, col, dstc, wbuf, Et);
    gemm16<<<dim3(3, mg), 256, 0, stream>>>(h1hi, h1lo, Wthi + 81920, Wtlo + 81920, hbuf16, Nn, 384, 448);
    aggL_k<6, 64, true, true><<<nb4, 256, 0, stream>>>(
        hbuf16, wbuf, b2, row_ptr, col, nullptr, h1hi, h1lo, Nn);
    alphaproj_k<6><<<nb4, 256, 0, stream>>>(h1hi, h1lo, Ps + 4864, Pd + 4864, aA, dA, Nn);

    // ---- layer 3: 384 -> 6x40 ----
    edgew_k<<<(Et * 8 + 255) / 256, 256, 0, stream>>>(aA, dA, col, dstc, wbuf, Et);
    gemm16<<<dim3(2, mg), 256, 0, stream>>>(h1hi, h1lo, Wthi + 253952, Wtlo + 253952, hbuf16, Nn, 240, 384);
    aggL_k<6, 40, false, false><<<nb4, 256, 0, stream>>>(
        hbuf16, wbuf, b3, row_ptr, col, out, nullptr, nullptr, Nn);
}

// Round 14
// 494.896 us; speedup vs baseline: 1.2817x; 1.0245x over previous
//
#include <hip/hip_runtime.h>
#include <hip/hip_bf16.h>

// ---------------------------------------------------------------------------
// 3-layer GAT forward (PyG GATConv, eval) on MI355X.
// All inter-layer tensors fp16 (h~ gather table AND post-agg h). The bf16
// hi/lo split needed by the 3-product MFMA GEMM is reconstructed EXACTLY
// from fp16 in the GEMM's LDS staging (fp16 mantissa ⊂ bf16hi+lo), halving
// agg writes, alphaproj reads, and GEMM A-reads vs stored-split.
// Agg: r13's lean loop (streaming e-indexed weights, single dependent
// gather, 24 VGPR). CSR: (dst, src-block)-keyed + hierarchical scan.
// ---------------------------------------------------------------------------

#define NFEAT 129
#define MPAD  30080   // 235 * 128
#define BLKSH 11
#define KPD   16

typedef __attribute__((ext_vector_type(8))) short short8v;
typedef __attribute__((ext_vector_type(8))) unsigned short u16x8;
typedef __attribute__((ext_vector_type(8))) __bf16 bf16x8;
typedef __attribute__((ext_vector_type(4))) float f32x4;
typedef unsigned short u16;

union FragU { short8v s; bf16x8 b; };

__device__ inline u16 f2bf(float x) {
    unsigned u = __builtin_bit_cast(unsigned, x);
    unsigned r = (u + 0x7fffu + ((u >> 16) & 1u)) >> 16;
    return (u16)r;
}
__device__ inline float bf2f(u16 b) {
    unsigned u = ((unsigned)b) << 16;
    return __builtin_bit_cast(float, u);
}
__device__ inline float h2f(u16 u) { return (float)__builtin_bit_cast(_Float16, u); }
__device__ inline u16 f2h(float v) { return __builtin_bit_cast(u16, (_Float16)v); }

// ---------------- CSR build (keyed by dst*KPD + src-block) ----------------

__global__ __launch_bounds__(256) void hist_k(const int* __restrict__ src,
                                              const int* __restrict__ dst,
                                              int* __restrict__ cnt, int E, int n) {
    int e = blockIdx.x * 256 + threadIdx.x;
    if (e < E + n) {
        int s, d;
        if (e < E) { s = src[e]; d = dst[e]; }
        else       { s = d = e - E; }
        atomicAdd(&cnt[d * KPD + (s >> BLKSH)], 1);
    }
}

__global__ __launch_bounds__(256) void bsum_k(const int* __restrict__ cnt,
                                              int* __restrict__ bsum, int nk) {
    __shared__ int sh[256];
    int t = threadIdx.x, idx = blockIdx.x * 256 + t;
    sh[t] = (idx < nk) ? cnt[idx] : 0;
    __syncthreads();
    for (int o = 128; o; o >>= 1) {
        if (t < o) sh[t] += sh[t + o];
        __syncthreads();
    }
    if (t == 0) bsum[blockIdx.x] = sh[0];
}

__global__ __launch_bounds__(1024) void bscan_k(const int* __restrict__ bsum,
                                                int* __restrict__ bofs, int nb) {
    __shared__ int part[1024];
    int t = threadIdx.x;
    int per = (nb + 1023) >> 10;
    int base = t * per;
    int s = 0;
    for (int j = 0; j < per; ++j) {
        int i = base + j;
        if (i < nb) s += bsum[i];
    }
    part[t] = s;
    __syncthreads();
    for (int o = 1; o < 1024; o <<= 1) {
        int v = 0;
        if (t >= o) v = part[t - o];
        __syncthreads();
        if (t >= o) part[t] += v;
        __syncthreads();
    }
    int run = (t > 0) ? part[t - 1] : 0;
    for (int j = 0; j < per; ++j) {
        int i = base + j;
        if (i < nb) { bofs[i] = run; run += bsum[i]; }
    }
    if (t == 1023) bofs[nb] = part[1023];
}

__global__ __launch_bounds__(256) void scanw_k(const int* __restrict__ cnt,
                                               const int* __restrict__ bofs,
                                               int* __restrict__ row_ptr, int nk) {
    __shared__ int sh[256];
    int t = threadIdx.x, idx = blockIdx.x * 256 + t;
    int v = (idx < nk) ? cnt[idx] : 0;
    sh[t] = v;
    __syncthreads();
    for (int o = 1; o < 256; o <<= 1) {
        int u = 0;
        if (t >= o) u = sh[t - o];
        __syncthreads();
        if (t >= o) sh[t] += u;
        __syncthreads();
    }
    if (idx < nk) row_ptr[idx] = bofs[blockIdx.x] + sh[t] - v;
    if (idx == nk - 1) row_ptr[nk] = bofs[blockIdx.x] + sh[t];
}

__global__ __launch_bounds__(256) void scatter_k(const int* __restrict__ src, const int* __restrict__ dst,
                                                 const int* __restrict__ row_ptr, int* __restrict__ fill,
                                                 int* __restrict__ col, int* __restrict__ dstc,
                                                 int E, int n) {
    int e = blockIdx.x * 256 + threadIdx.x;
    if (e < E + n) {
        int s, d;
        if (e < E) { s = src[e]; d = dst[e]; }
        else       { s = d = e - E; }
        int key = d * KPD + (s >> BLKSH);
        int pos = row_ptr[key] + atomicAdd(&fill[key], 1);
        col[pos] = s;
        dstc[pos] = d;
    }
}

// ---------------- input split (fp32 -> bf16 hi/lo), row+K padded -----------

__global__ __launch_bounds__(256) void xsplit_k(const float* __restrict__ in,
                                                u16* __restrict__ hi, u16* __restrict__ lo,
                                                int Nn, int K, int Kp, int Mp) {
    int idx = blockIdx.x * 256 + threadIdx.x;
    if (idx >= Mp * Kp) return;
    int m = idx / Kp, k = idx - m * Kp;
    float v = (m < Nn && k < K) ? in[(size_t)m * K + k] : 0.f;
    u16 h = f2bf(v);
    hi[idx] = h;
    lo[idx] = f2bf(v - bf2f(h));
}

// ---------------- all three W splits (transposed, padded) ------------------
// seg1 W1t: [512 x 160] @ 0 ; seg2 W2t: [384 x 448] @ 81920 ;
// seg3 W3t: [256 x 384] @ 253952 (total 352256)

__global__ __launch_bounds__(256) void wsplitAll_k(const float* __restrict__ W1,
                                                   const float* __restrict__ W2,
                                                   const float* __restrict__ W3,
                                                   u16* __restrict__ hi, u16* __restrict__ lo) {
    int idx = blockIdx.x * 256 + threadIdx.x;
    if (idx >= 352256) return;
    const float* W; int loc, Kp, K, N;
    if (idx < 81920)       { W = W1; loc = idx;          Kp = 160; K = 129; N = 448; }
    else if (idx < 253952) { W = W2; loc = idx - 81920;  Kp = 448; K = 448; N = 384; }
    else                   { W = W3; loc = idx - 253952; Kp = 384; K = 384; N = 240; }
    int nn = loc / Kp, k = loc - nn * Kp;
    float v = (k < K && nn < N) ? W[(size_t)k * N + nn] : 0.f;
    u16 h = f2bf(v);
    hi[idx] = h;
    lo[idx] = f2bf(v - bf2f(h));
}

// ---------------- projection tables P[k][h] ----------------
// P1 rows [0,160), P2 rows [160,608), P3 rows [608,992).

__global__ __launch_bounds__(256) void projAll_k(
    const float* __restrict__ W1, const float* __restrict__ a1s, const float* __restrict__ a1d,
    const float* __restrict__ W2, const float* __restrict__ a2s, const float* __restrict__ a2d,
    const float* __restrict__ W3, const float* __restrict__ a3s, const float* __restrict__ a3d,
    float* __restrict__ Ps, float* __restrict__ Pd) {
    int idx = blockIdx.x * 256 + threadIdx.x;
    if (idx >= 992 * 8) return;
    int row = idx >> 3, h = idx & 7;
    const float *W, *as_, *ad_; int k, K, Ncols, H, C;
    if (row < 160)      { k = row;       K = 129; W = W1; as_ = a1s; ad_ = a1d; Ncols = 448; H = 7; C = 64; }
    else if (row < 608) { k = row - 160; K = 448; W = W2; as_ = a2s; ad_ = a2d; Ncols = 384; H = 6; C = 64; }
    else                { k = row - 608; K = 384; W = W3; as_ = a3s; ad_ = a3d; Ncols = 240; H = 6; C = 40; }
    float ps = 0.f, pd = 0.f;
    if (h < H && k < K) {
        const float* wr = W + (size_t)k * Ncols + h * C;
        const float* ar = as_ + h * C;
        const float* dr = ad_ + h * C;
        for (int c = 0; c < C; ++c) {
            float wv = wr[c];
            ps += wv * ar[c];
            pd += wv * dr[c];
        }
    }
    Ps[idx] = ps;
    Pd[idx] = pd;
}

// ---------------- zero pad rows of both fp16 h buffers ---------------------

__global__ __launch_bounds__(256) void zeropads_k(u16* __restrict__ hA, u16* __restrict__ hB,
                                                  int Nn) {
    int totA = (MPAD - Nn) * 448;
    int totB = (MPAD - Nn) * 384;
    int idx = blockIdx.x * 256 + threadIdx.x;
    if (idx < totA) hA[(size_t)Nn * 448 + idx] = 0;
    if (idx < totB) hB[(size_t)Nn * 384 + idx] = 0;
}

// ---------------- layer-1 alphas: (x @ P1) ----------------

__global__ __launch_bounds__(256) void alpha1_k(const float* __restrict__ x,
                                                const float* __restrict__ Ps,
                                                const float* __restrict__ Pd,
                                                float* __restrict__ oS, float* __restrict__ oD, int n) {
    int wv = threadIdx.x >> 6, lane = threadIdx.x & 63;
    int i = blockIdx.x * 4 + wv;
    if (i >= n) return;
    const float* row = x + (size_t)i * NFEAT;
    float x0 = row[lane], x1 = row[64 + lane];
    float ps[8], pd[8];
    #pragma unroll
    for (int h = 0; h < 8; ++h) {
        ps[h] = x0 * Ps[lane * 8 + h] + x1 * Ps[(64 + lane) * 8 + h];
        pd[h] = x0 * Pd[lane * 8 + h] + x1 * Pd[(64 + lane) * 8 + h];
    }
    if (lane == 0) {
        float x2 = row[128];
        #pragma unroll
        for (int h = 0; h < 8; ++h) {
            ps[h] += x2 * Ps[128 * 8 + h];
            pd[h] += x2 * Pd[128 * 8 + h];
        }
    }
    #pragma unroll
    for (int h = 0; h < 8; ++h) {
        #pragma unroll
        for (int off = 32; off; off >>= 1) {
            ps[h] += __shfl_xor(ps[h], off);
            pd[h] += __shfl_xor(pd[h], off);
        }
    }
    if (lane == 0) {
        #pragma unroll
        for (int h = 0; h < 8; ++h) {
            oS[(size_t)i * 8 + h] = ps[h];
            oD[(size_t)i * 8 + h] = pd[h];
        }
    }
}

// ---------------- alphas for layers 2/3 from fp16 h ----------------

template <int KC>
__global__ __launch_bounds__(256) void alphaproj_k(const u16* __restrict__ H16,
                                                   const float* __restrict__ Ps,
                                                   const float* __restrict__ Pd,
                                                   float* __restrict__ oS, float* __restrict__ oD, int n) {
    constexpr int STRIDE = KC * 64;
    int wv = threadIdx.x >> 6, lane = threadIdx.x & 63;
    int i = blockIdx.x * 4 + wv;
    if (i >= n) return;
    const u16* hr = H16 + (size_t)i * STRIDE;
    float ps[8] = {}, pd[8] = {};
    #pragma unroll
    for (int kc = 0; kc < KC; ++kc) {
        int k = kc * 64 + lane;
        float v = h2f(hr[k]);
        #pragma unroll
        for (int h = 0; h < 8; ++h) {
            ps[h] += v * Ps[k * 8 + h];
            pd[h] += v * Pd[k * 8 + h];
        }
    }
    #pragma unroll
    for (int h = 0; h < 8; ++h) {
        #pragma unroll
        for (int off = 32; off; off >>= 1) {
            ps[h] += __shfl_xor(ps[h], off);
            pd[h] += __shfl_xor(pd[h], off);
        }
    }
    if (lane == 0) {
        #pragma unroll
        for (int h = 0; h < 8; ++h) {
            oS[(size_t)i * 8 + h] = ps[h];
            oD[(size_t)i * 8 + h] = pd[h];
        }
    }
}

// ---------------- per-edge weights: w[e][h] = exp(lrelu(as[src]+ad[dst])) ---

__global__ __launch_bounds__(256) void edgew_k(const float* __restrict__ as_,
                                               const float* __restrict__ ad_,
                                               const int* __restrict__ col,
                                               const int* __restrict__ dstc,
                                               float* __restrict__ w, int Et) {
    int idx = blockIdx.x * 256 + threadIdx.x;
    if (idx >= Et * 8) return;
    int e = idx >> 3, h = idx & 7;
    int s = col[e], d = dstc[e];
    float v = as_[(size_t)s * 8 + h] + ad_[(size_t)d * 8 + h];
    v = v > 0.f ? v : 0.2f * v;
    w[idx] = __expf(v);
}

// ---------------- LDS swizzle helper ----------------

__device__ __forceinline__ int swz(int r, int s) {
    return (r << 2) | ((s ^ (r & 3) ^ ((r >> 2) & 3)) & 3);
}

// ---------------- split MFMA GEMM, fp16 output ----------------
// Tile 128x128, BK=32, 4 waves (2m x 2n), 3 MFMAs per hi/lo pair.
// ASPLIT=true: A pre-split (Ahi/Alo). ASPLIT=false: A fp16, split in staging
// (exact: fp16 mantissa fits in bf16hi+bf16lo).

template <bool ASPLIT>
__global__ __launch_bounds__(256) void gemm16(
    const u16* __restrict__ Ahi, const u16* __restrict__ Alo,
    const u16* __restrict__ A16,
    const u16* __restrict__ Bhi, const u16* __restrict__ Blo,
    u16* __restrict__ C16, int M, int Ncols, int Kp)
{
    __shared__ __align__(16) u16 sAh[128 * 32];
    __shared__ __align__(16) u16 sAl[128 * 32];
    __shared__ __align__(16) u16 sBh[128 * 32];
    __shared__ __align__(16) u16 sBl[128 * 32];
    const int tid = threadIdx.x;
    const int m0 = blockIdx.y * 128;
    const int n0 = blockIdx.x * 128;
    const int lane = tid & 63, wave = tid >> 6;
    const int wm = wave >> 1, wn = wave & 1;
    const int l15 = lane & 15, lg = lane >> 4;
    const int r0 = tid >> 2, s0 = tid & 3;
    const int w0 = swz(r0, s0), w1 = swz(r0 + 64, s0);
    f32x4 acc[4][4] = {};

    for (int k0 = 0; k0 < Kp; k0 += 32) {
        size_t gA0 = (size_t)(m0 + r0) * Kp + k0 + s0 * 8;
        size_t gA1 = (size_t)(m0 + r0 + 64) * Kp + k0 + s0 * 8;
        size_t gB0 = (size_t)(n0 + r0) * Kp + k0 + s0 * 8;
        size_t gB1 = (size_t)(n0 + r0 + 64) * Kp + k0 + s0 * 8;
        short8v ah0, ah1, al0, al1;
        if constexpr (ASPLIT) {
            ah0 = *(const short8v*)(Ahi + gA0);
            ah1 = *(const short8v*)(Ahi + gA1);
            al0 = *(const short8v*)(Alo + gA0);
            al1 = *(const short8v*)(Alo + gA1);
        } else {
            u16x8 a0 = *(const u16x8*)(A16 + gA0);
            u16x8 a1 = *(const u16x8*)(A16 + gA1);
            #pragma unroll
            for (int j = 0; j < 8; ++j) {
                float f0 = h2f(a0[j]);
                u16 h0 = f2bf(f0);
                ah0[j] = (short)h0;
                al0[j] = (short)f2bf(f0 - bf2f(h0));
                float f1 = h2f(a1[j]);
                u16 h1 = f2bf(f1);
                ah1[j] = (short)h1;
                al1[j] = (short)f2bf(f1 - bf2f(h1));
            }
        }
        short8v bh0 = *(const short8v*)(Bhi + gB0);
        short8v bh1 = *(const short8v*)(Bhi + gB1);
        short8v bl0 = *(const short8v*)(Blo + gB0);
        short8v bl1 = *(const short8v*)(Blo + gB1);
        __syncthreads();
        ((short8v*)sAh)[w0] = ah0; ((short8v*)sAh)[w1] = ah1;
        ((short8v*)sAl)[w0] = al0; ((short8v*)sAl)[w1] = al1;
        ((short8v*)sBh)[w0] = bh0; ((short8v*)sBh)[w1] = bh1;
        ((short8v*)sBl)[w0] = bl0; ((short8v*)sBl)[w1] = bl1;
        __syncthreads();
        FragU fah[4], fal[4], fbh[4], fbl[4];
        #pragma unroll
        for (int mf = 0; mf < 4; ++mf) {
            int rr = wm * 64 + mf * 16 + l15;
            int idx = swz(rr, lg);
            fah[mf].s = ((const short8v*)sAh)[idx];
            fal[mf].s = ((const short8v*)sAl)[idx];
        }
        #pragma unroll
        for (int nf = 0; nf < 4; ++nf) {
            int rr = wn * 64 + nf * 16 + l15;
            int idx = swz(rr, lg);
            fbh[nf].s = ((const short8v*)sBh)[idx];
            fbl[nf].s = ((const short8v*)sBl)[idx];
        }
        #pragma unroll
        for (int mf = 0; mf < 4; ++mf) {
            #pragma unroll
            for (int nf = 0; nf < 4; ++nf) {
                acc[mf][nf] = __builtin_amdgcn_mfma_f32_16x16x32_bf16(fah[mf].b, fbh[nf].b, acc[mf][nf], 0, 0, 0);
                acc[mf][nf] = __builtin_amdgcn_mfma_f32_16x16x32_bf16(fah[mf].b, fbl[nf].b, acc[mf][nf], 0, 0, 0);
                acc[mf][nf] = __builtin_amdgcn_mfma_f32_16x16x32_bf16(fal[mf].b, fbh[nf].b, acc[mf][nf], 0, 0, 0);
            }
        }
    }
    #pragma unroll
    for (int mf = 0; mf < 4; ++mf) {
        #pragma unroll
        for (int nf = 0; nf < 4; ++nf) {
            int colg = n0 + wn * 64 + nf * 16 + l15;
            if (colg >= Ncols) continue;
            #pragma unroll
            for (int r = 0; r < 4; ++r) {
                int rowg = m0 + wm * 64 + mf * 16 + lg * 4 + r;
                if (rowg < M) C16[(size_t)rowg * Ncols + colg] = f2h(acc[mf][nf][r]);
            }
        }
    }
}

// ---------------- lean agg: fp16 table + streaming weights ----------------
// wave per node; lane owns 8 consecutive fp16 channels (16B load/edge).
// Single dependent load level (col -> hf); w[e*8+h] is an e-indexed stream.
// F16OUT: write post-agg h as fp16 (half the bytes of stored-split).

template <int H, int C, bool RELU, bool F16OUT>
__global__ __launch_bounds__(256) void aggL_k(
    const u16* __restrict__ hf, const float* __restrict__ w,
    const float* __restrict__ bias,
    const int* __restrict__ row_ptr, const int* __restrict__ col,
    float* __restrict__ outf, u16* __restrict__ oh16, int n)
{
    constexpr int HC = H * C;
    constexpr int LACT = HC / 8;
    const int wv = threadIdx.x >> 6, lane = threadIdx.x & 63;
    const int i = blockIdx.x * 4 + wv;
    if (i >= n) return;
    const int ch0 = lane * 8;
    const bool act = lane < LACT;
    const int h = act ? (ch0 / C) : 0;
    const bool lead = act && ((ch0 % C) == 0);
    const int beg = row_ptr[i * KPD], end = row_ptr[(i + 1) * KPD];
    float acc[8] = {};
    float dp = 0.f;
    if (act) {
        int e = beg;
        for (; e + 2 <= end; e += 2) {
            int sA = col[e], sB = col[e + 1];
            float wA = w[(size_t)e * 8 + h];
            float wB = w[(size_t)(e + 1) * 8 + h];
            u16x8 vA = *(const u16x8*)(hf + (size_t)sA * HC + ch0);
            u16x8 vB = *(const u16x8*)(hf + (size_t)sB * HC + ch0);
            #pragma unroll
            for (int j = 0; j < 8; ++j)
                acc[j] += wA * h2f(vA[j]) + wB * h2f(vB[j]);
            if (lead) dp += wA + wB;
        }
        if (e < end) {
            int sA = col[e];
            float wA = w[(size_t)e * 8 + h];
            u16x8 vA = *(const u16x8*)(hf + (size_t)sA * HC + ch0);
            #pragma unroll
            for (int j = 0; j < 8; ++j)
                acc[j] += wA * h2f(vA[j]);
            if (lead) dp += wA;
        }
    }
    const float den = __shfl(dp, h * (C / 8)) + 1e-16f;
    if (act) {
        float o[8];
        #pragma unroll
        for (int j = 0; j < 8; ++j) {
            float v = acc[j] / den + bias[ch0 + j];
            if (RELU) v = fmaxf(v, 0.f);
            o[j] = v;
        }
        size_t base = (size_t)i * HC + ch0;
        if constexpr (F16OUT) {
            u16x8 po;
            #pragma unroll
            for (int j = 0; j < 8; ++j) po[j] = f2h(o[j]);
            *(u16x8*)(oh16 + base) = po;
        } else {
            float4 q0; q0.x = o[0]; q0.y = o[1]; q0.z = o[2]; q0.w = o[3];
            float4 q1; q1.x = o[4]; q1.y = o[5]; q1.z = o[6]; q1.w = o[7];
            *(float4*)(outf + base) = q0;
            *(float4*)(outf + base + 4) = q1;
        }
    }
}

// ---------------------------------------------------------------------------

extern "C" void kernel_launch(void* const* d_in, const int* in_sizes, int n_in,
                              void* d_out, int out_size, void* d_ws, size_t ws_size,
                              hipStream_t stream) {
    const float* x   = (const float*)d_in[0];
    const int*   ei  = (const int*)d_in[1];
    const float* W1  = (const float*)d_in[2];
    const float* a1s = (const float*)d_in[3];
    const float* a1d = (const float*)d_in[4];
    const float* b1  = (const float*)d_in[5];
    const float* W2  = (const float*)d_in[6];
    const float* a2s = (const float*)d_in[7];
    const float* a2d = (const float*)d_in[8];
    const float* b2  = (const float*)d_in[9];
    const float* W3  = (const float*)d_in[10];
    const float* a3s = (const float*)d_in[11];
    const float* a3d = (const float*)d_in[12];
    const float* b3  = (const float*)d_in[13];
    float* out = (float*)d_out;

    const int Nn = in_sizes[0] / NFEAT;   // 30000
    const int E  = in_sizes[1] / 2;       // 480000
    const int Et = E + Nn;
    const int NK = Nn * KPD;
    const int NB = (NK + 255) / 256;
    const int* srcp = ei;
    const int* dstp = ei + E;

    char* ws = (char*)d_ws;
    size_t off = 0;
    auto carve = [&](size_t bytes) -> char* {
        char* p = ws + off;
        off += (bytes + 255) & ~(size_t)255;
        return p;
    };
    u16*   hbuf16 = (u16*)carve((size_t)MPAD * 448 * 2);   // h~ fp16 (all layers)
    u16*   hA16  = (u16*)carve((size_t)MPAD * 448 * 2);    // h1 fp16 (stride 448)
    u16*   hB16  = (u16*)carve((size_t)MPAD * 384 * 2);    // h2 fp16 (stride 384)
    u16*   Xhi   = (u16*)carve((size_t)MPAD * 160 * 2);
    u16*   Xlo   = (u16*)carve((size_t)MPAD * 160 * 2);
    u16*   Wthi  = (u16*)carve((size_t)352256 * 2);
    u16*   Wtlo  = (u16*)carve((size_t)352256 * 2);
    float* wbuf  = (float*)carve((size_t)Et * 8 * 4);
    int*   col   = (int*)carve((size_t)Et * 4);
    int*   dstc  = (int*)carve((size_t)Et * 4);
    int* row_ptr = (int*)carve((size_t)(NK + 1) * 4);
    int*   cnt   = (int*)carve((size_t)NK * 4);
    int*   bsum  = (int*)carve((size_t)NB * 4);
    int*   bofs  = (int*)carve((size_t)(NB + 1) * 4);
    float* aA    = (float*)carve((size_t)Nn * 8 * 4);
    float* dA    = (float*)carve((size_t)Nn * 8 * 4);
    float* aB    = (float*)carve((size_t)Nn * 8 * 4);
    float* dB    = (float*)carve((size_t)Nn * 8 * 4);
    float* Ps    = (float*)carve((size_t)992 * 8 * 4);
    float* Pd    = (float*)carve((size_t)992 * 8 * 4);
    (void)ws_size;

    const int nb4 = (Nn + 3) / 4;   // 7500
    const int mg  = MPAD / 128;     // 235

    // ---- CSR keyed by (dst, src-block) ----
    hipMemsetAsync(cnt, 0, (size_t)NK * 4, stream);
    hist_k<<<(Et + 255) / 256, 256, 0, stream>>>(srcp, dstp, cnt, E, Nn);
    bsum_k<<<NB, 256, 0, stream>>>(cnt, bsum, NK);
    bscan_k<<<1, 1024, 0, stream>>>(bsum, bofs, NB);
    scanw_k<<<NB, 256, 0, stream>>>(cnt, bofs, row_ptr, NK);
    hipMemsetAsync(cnt, 0, (size_t)NK * 4, stream);
    scatter_k<<<(Et + 255) / 256, 256, 0, stream>>>(srcp, dstp, row_ptr, cnt, col, dstc, E, Nn);

    // ---- input prep ----
    xsplit_k<<<((MPAD * 160) + 255) / 256, 256, 0, stream>>>(x, Xhi, Xlo, Nn, NFEAT, 160, MPAD);
    wsplitAll_k<<<(352256 + 255) / 256, 256, 0, stream>>>(W1, W2, W3, Wthi, Wtlo);
    projAll_k<<<(992 * 8 + 255) / 256, 256, 0, stream>>>(W1, a1s, a1d, W2, a2s, a2d, W3, a3s, a3d, Ps, Pd);
    zeropads_k<<<(((MPAD - Nn) * 448) + 255) / 256, 256, 0, stream>>>(hA16, hB16, Nn);

    // ---- layer 1: x(129) -> 7x64 ----
    alpha1_k<<<nb4, 256, 0, stream>>>(x, Ps, Pd, aA, dA, Nn);
    edgew_k<<<(Et * 8 + 255) / 256, 256, 0, stream>>>(aA, dA, col, dstc, wbuf, Et);
    gemm16<true><<<dim3(4, mg), 256, 0, stream>>>(Xhi, Xlo, nullptr, Wthi, Wtlo,
                                                  hbuf16, Nn, 448, 160);
    aggL_k<7, 64, true, true><<<nb4, 256, 0, stream>>>(
        hbuf16, wbuf, b1, row_ptr, col, nullptr, hA16, Nn);
    alphaproj_k<7><<<nb4, 256, 0, stream>>>(hA16, Ps + 1280, Pd + 1280, aB, dB, Nn);

    // ---- layer 2: 448 -> 6x64 ----
    edgew_k<<<(Et * 8 + 255) / 256, 256, 0, stream>>>(aB, dB, col, dstc, wbuf, Et);
    gemm16<false><<<dim3(3, mg), 256, 0, stream>>>(nullptr, nullptr, hA16,
                                                   Wthi + 81920, Wtlo + 81920,
                                                   hbuf16, Nn, 384, 448);
    aggL_k<6, 64, true, true><<<nb4, 256, 0, stream>>>(
        hbuf16, wbuf, b2, row_ptr, col, nullptr, hB16, Nn);
    alphaproj_k<6><<<nb4, 256, 0, stream>>>(hB16, Ps + 4864, Pd + 4864, aA, dA, Nn);

    // ---- layer 3: 384 -> 6x40 ----
    edgew_k<<<(Et * 8 + 255) / 256, 256, 0, stream>>>(aA, dA, col, dstc, wbuf, Et);
    gemm16<false><<<dim3(2, mg), 256, 0, stream>>>(nullptr, nullptr, hB16,
                                                   Wthi + 253952, Wtlo + 253952,
                                                   hbuf16, Nn, 240, 384);
    aggL_k<6, 40, false, false><<<nb4, 256, 0, stream>>>(
        hbuf16, wbuf, b3, row_ptr, col, out, nullptr, Nn);
}

// Round 15
// 492.638 us; speedup vs baseline: 1.2876x; 1.0046x over previous
//
#include <hip/hip_runtime.h>
#include <hip/hip_bf16.h>

// ---------------------------------------------------------------------------
// 3-layer GAT forward (PyG GATConv, eval) on MI355X.
// All inter-layer tensors fp16; bf16 hi/lo split for the 3-product MFMA GEMM
// reconstructed exactly from fp16 in GEMM staging. Agg = lean loop
// (streaming e-indexed weights, single dependent gather, 24 VGPR) — at its
// compulsory cross-XCD traffic floor. Plain dst-keyed CSR (src-block
// clustering measured null) + hierarchical scan. Prep fused into 1 kernel.
// ---------------------------------------------------------------------------

#define NFEAT 129
#define MPAD  30080   // 235 * 128

typedef __attribute__((ext_vector_type(8))) short short8v;
typedef __attribute__((ext_vector_type(8))) unsigned short u16x8;
typedef __attribute__((ext_vector_type(8))) __bf16 bf16x8;
typedef __attribute__((ext_vector_type(4))) float f32x4;
typedef unsigned short u16;

union FragU { short8v s; bf16x8 b; };

__device__ inline u16 f2bf(float x) {
    unsigned u = __builtin_bit_cast(unsigned, x);
    unsigned r = (u + 0x7fffu + ((u >> 16) & 1u)) >> 16;
    return (u16)r;
}
__device__ inline float bf2f(u16 b) {
    unsigned u = ((unsigned)b) << 16;
    return __builtin_bit_cast(float, u);
}
__device__ inline float h2f(u16 u) { return (float)__builtin_bit_cast(_Float16, u); }
__device__ inline u16 f2h(float v) { return __builtin_bit_cast(u16, (_Float16)v); }

// ---------------- CSR build (plain dst keys) ----------------

__global__ __launch_bounds__(256) void hist_k(const int* __restrict__ dst,
                                              int* __restrict__ cnt, int E, int n) {
    int e = blockIdx.x * 256 + threadIdx.x;
    if (e < E + n) {
        int d = (e < E) ? dst[e] : (e - E);
        atomicAdd(&cnt[d], 1);
    }
}

__global__ __launch_bounds__(256) void bsum_k(const int* __restrict__ cnt,
                                              int* __restrict__ bsum, int nk) {
    __shared__ int sh[256];
    int t = threadIdx.x, idx = blockIdx.x * 256 + t;
    sh[t] = (idx < nk) ? cnt[idx] : 0;
    __syncthreads();
    for (int o = 128; o; o >>= 1) {
        if (t < o) sh[t] += sh[t + o];
        __syncthreads();
    }
    if (t == 0) bsum[blockIdx.x] = sh[0];
}

__global__ __launch_bounds__(1024) void bscan_k(const int* __restrict__ bsum,
                                                int* __restrict__ bofs, int nb) {
    __shared__ int part[1024];
    int t = threadIdx.x;
    int per = (nb + 1023) >> 10;
    int base = t * per;
    int s = 0;
    for (int j = 0; j < per; ++j) {
        int i = base + j;
        if (i < nb) s += bsum[i];
    }
    part[t] = s;
    __syncthreads();
    for (int o = 1; o < 1024; o <<= 1) {
        int v = 0;
        if (t >= o) v = part[t - o];
        __syncthreads();
        if (t >= o) part[t] += v;
        __syncthreads();
    }
    int run = (t > 0) ? part[t - 1] : 0;
    for (int j = 0; j < per; ++j) {
        int i = base + j;
        if (i < nb) { bofs[i] = run; run += bsum[i]; }
    }
    if (t == 1023) bofs[nb] = part[1023];
}

__global__ __launch_bounds__(256) void scanw_k(const int* __restrict__ cnt,
                                               const int* __restrict__ bofs,
                                               int* __restrict__ row_ptr, int nk) {
    __shared__ int sh[256];
    int t = threadIdx.x, idx = blockIdx.x * 256 + t;
    int v = (idx < nk) ? cnt[idx] : 0;
    sh[t] = v;
    __syncthreads();
    for (int o = 1; o < 256; o <<= 1) {
        int u = 0;
        if (t >= o) u = sh[t - o];
        __syncthreads();
        if (t >= o) sh[t] += u;
        __syncthreads();
    }
    if (idx < nk) row_ptr[idx] = bofs[blockIdx.x] + sh[t] - v;
    if (idx == nk - 1) row_ptr[nk] = bofs[blockIdx.x] + sh[t];
}

__global__ __launch_bounds__(256) void scatter_k(const int* __restrict__ src, const int* __restrict__ dst,
                                                 const int* __restrict__ row_ptr, int* __restrict__ fill,
                                                 int* __restrict__ col, int* __restrict__ dstc,
                                                 int E, int n) {
    int e = blockIdx.x * 256 + threadIdx.x;
    if (e < E + n) {
        int s, d;
        if (e < E) { s = src[e]; d = dst[e]; }
        else       { s = d = e - E; }
        int pos = row_ptr[d] + atomicAdd(&fill[d], 1);
        col[pos] = s;
        dstc[pos] = d;
    }
}

// ---------------- fused prep: xsplit + wsplitAll + projAll + zeropads ------
// idx space: [0, MPAD*160)               -> x split (fp32 -> bf16 hi/lo)
//            [S1, S1+352256)             -> W splits (transposed, padded)
//            [S2, S2+992*8)              -> projection tables
//            [S3, S3+(MPAD-Nn)*448)      -> hA16 pad rows zero
//            [S4, S4+(MPAD-Nn)*384)      -> hB16 pad rows zero

__global__ __launch_bounds__(256) void prep_k(
    const float* __restrict__ x,
    const float* __restrict__ W1, const float* __restrict__ a1s, const float* __restrict__ a1d,
    const float* __restrict__ W2, const float* __restrict__ a2s, const float* __restrict__ a2d,
    const float* __restrict__ W3, const float* __restrict__ a3s, const float* __restrict__ a3d,
    u16* __restrict__ Xhi, u16* __restrict__ Xlo,
    u16* __restrict__ Whi, u16* __restrict__ Wlo,
    float* __restrict__ Ps, float* __restrict__ Pd,
    u16* __restrict__ hA, u16* __restrict__ hB, int Nn)
{
    const int S1 = MPAD * 160;
    const int S2 = S1 + 352256;
    const int S3 = S2 + 992 * 8;
    const int S4 = S3 + (MPAD - 30000) * 448;
    const int S5 = S4 + (MPAD - 30000) * 384;
    int idx = blockIdx.x * 256 + threadIdx.x;
    if (idx < S1) {
        int m = idx / 160, k = idx - m * 160;
        float v = (m < Nn && k < NFEAT) ? x[(size_t)m * NFEAT + k] : 0.f;
        u16 h = f2bf(v);
        Xhi[idx] = h;
        Xlo[idx] = f2bf(v - bf2f(h));
    } else if (idx < S2) {
        int loc0 = idx - S1;
        const float* W; int loc, Kp, K, N;
        if (loc0 < 81920)       { W = W1; loc = loc0;          Kp = 160; K = 129; N = 448; }
        else if (loc0 < 253952) { W = W2; loc = loc0 - 81920;  Kp = 448; K = 448; N = 384; }
        else                    { W = W3; loc = loc0 - 253952; Kp = 384; K = 384; N = 240; }
        int nn = loc / Kp, k = loc - nn * Kp;
        float v = (k < K && nn < N) ? W[(size_t)k * N + nn] : 0.f;
        u16 h = f2bf(v);
        Whi[loc0] = h;
        Wlo[loc0] = f2bf(v - bf2f(h));
    } else if (idx < S3) {
        int loc0 = idx - S2;
        int row = loc0 >> 3, h = loc0 & 7;
        const float *W, *as_, *ad_; int k, K, Ncols, H, C;
        if (row < 160)      { k = row;       K = 129; W = W1; as_ = a1s; ad_ = a1d; Ncols = 448; H = 7; C = 64; }
        else if (row < 608) { k = row - 160; K = 448; W = W2; as_ = a2s; ad_ = a2d; Ncols = 384; H = 6; C = 64; }
        else                { k = row - 608; K = 384; W = W3; as_ = a3s; ad_ = a3d; Ncols = 240; H = 6; C = 40; }
        float ps = 0.f, pd = 0.f;
        if (h < H && k < K) {
            const float* wr = W + (size_t)k * Ncols + h * C;
            const float* ar = as_ + h * C;
            const float* dr = ad_ + h * C;
            for (int c = 0; c < C; ++c) {
                float wv = wr[c];
                ps += wv * ar[c];
                pd += wv * dr[c];
            }
        }
        Ps[loc0] = ps;
        Pd[loc0] = pd;
    } else if (idx < S4) {
        hA[(size_t)Nn * 448 + (idx - S3)] = 0;
    } else if (idx < S5) {
        hB[(size_t)Nn * 384 + (idx - S4)] = 0;
    }
}

// ---------------- layer-1 alphas: (x @ P1) ----------------

__global__ __launch_bounds__(256) void alpha1_k(const float* __restrict__ x,
                                                const float* __restrict__ Ps,
                                                const float* __restrict__ Pd,
                                                float* __restrict__ oS, float* __restrict__ oD, int n) {
    int wv = threadIdx.x >> 6, lane = threadIdx.x & 63;
    int i = blockIdx.x * 4 + wv;
    if (i >= n) return;
    const float* row = x + (size_t)i * NFEAT;
    float x0 = row[lane], x1 = row[64 + lane];
    float ps[8], pd[8];
    #pragma unroll
    for (int h = 0; h < 8; ++h) {
        ps[h] = x0 * Ps[lane * 8 + h] + x1 * Ps[(64 + lane) * 8 + h];
        pd[h] = x0 * Pd[lane * 8 + h] + x1 * Pd[(64 + lane) * 8 + h];
    }
    if (lane == 0) {
        float x2 = row[128];
        #pragma unroll
        for (int h = 0; h < 8; ++h) {
            ps[h] += x2 * Ps[128 * 8 + h];
            pd[h] += x2 * Pd[128 * 8 + h];
        }
    }
    #pragma unroll
    for (int h = 0; h < 8; ++h) {
        #pragma unroll
        for (int off = 32; off; off >>= 1) {
            ps[h] += __shfl_xor(ps[h], off);
            pd[h] += __shfl_xor(pd[h], off);
        }
    }
    if (lane == 0) {
        #pragma unroll
        for (int h = 0; h < 8; ++h) {
            oS[(size_t)i * 8 + h] = ps[h];
            oD[(size_t)i * 8 + h] = pd[h];
        }
    }
}

// ---------------- alphas for layers 2/3 from fp16 h ----------------

template <int KC>
__global__ __launch_bounds__(256) void alphaproj_k(const u16* __restrict__ H16,
                                                   const float* __restrict__ Ps,
                                                   const float* __restrict__ Pd,
                                                   float* __restrict__ oS, float* __restrict__ oD, int n) {
    constexpr int STRIDE = KC * 64;
    int wv = threadIdx.x >> 6, lane = threadIdx.x & 63;
    int i = blockIdx.x * 4 + wv;
    if (i >= n) return;
    const u16* hr = H16 + (size_t)i * STRIDE;
    float ps[8] = {}, pd[8] = {};
    #pragma unroll
    for (int kc = 0; kc < KC; ++kc) {
        int k = kc * 64 + lane;
        float v = h2f(hr[k]);
        #pragma unroll
        for (int h = 0; h < 8; ++h) {
            ps[h] += v * Ps[k * 8 + h];
            pd[h] += v * Pd[k * 8 + h];
        }
    }
    #pragma unroll
    for (int h = 0; h < 8; ++h) {
        #pragma unroll
        for (int off = 32; off; off >>= 1) {
            ps[h] += __shfl_xor(ps[h], off);
            pd[h] += __shfl_xor(pd[h], off);
        }
    }
    if (lane == 0) {
        #pragma unroll
        for (int h = 0; h < 8; ++h) {
            oS[(size_t)i * 8 + h] = ps[h];
            oD[(size_t)i * 8 + h] = pd[h];
        }
    }
}

// ---------------- per-edge weights: w[e][h] = exp(lrelu(as[src]+ad[dst])) ---

__global__ __launch_bounds__(256) void edgew_k(const float* __restrict__ as_,
                                               const float* __restrict__ ad_,
                                               const int* __restrict__ col,
                                               const int* __restrict__ dstc,
                                               float* __restrict__ w, int Et) {
    int idx = blockIdx.x * 256 + threadIdx.x;
    if (idx >= Et * 8) return;
    int e = idx >> 3, h = idx & 7;
    int s = col[e], d = dstc[e];
    float v = as_[(size_t)s * 8 + h] + ad_[(size_t)d * 8 + h];
    v = v > 0.f ? v : 0.2f * v;
    w[idx] = __expf(v);
}

// ---------------- LDS swizzle helper ----------------

__device__ __forceinline__ int swz(int r, int s) {
    return (r << 2) | ((s ^ (r & 3) ^ ((r >> 2) & 3)) & 3);
}

// ---------------- split MFMA GEMM, fp16 output ----------------
// Tile 128x128, BK=32, 4 waves (2m x 2n), 3 MFMAs per hi/lo pair.
// ASPLIT=true: A pre-split (Ahi/Alo). ASPLIT=false: A fp16, split in staging.

template <bool ASPLIT>
__global__ __launch_bounds__(256) void gemm16(
    const u16* __restrict__ Ahi, const u16* __restrict__ Alo,
    const u16* __restrict__ A16,
    const u16* __restrict__ Bhi, const u16* __restrict__ Blo,
    u16* __restrict__ C16, int M, int Ncols, int Kp)
{
    __shared__ __align__(16) u16 sAh[128 * 32];
    __shared__ __align__(16) u16 sAl[128 * 32];
    __shared__ __align__(16) u16 sBh[128 * 32];
    __shared__ __align__(16) u16 sBl[128 * 32];
    const int tid = threadIdx.x;
    const int m0 = blockIdx.y * 128;
    const int n0 = blockIdx.x * 128;
    const int lane = tid & 63, wave = tid >> 6;
    const int wm = wave >> 1, wn = wave & 1;
    const int l15 = lane & 15, lg = lane >> 4;
    const int r0 = tid >> 2, s0 = tid & 3;
    const int w0 = swz(r0, s0), w1 = swz(r0 + 64, s0);
    f32x4 acc[4][4] = {};

    for (int k0 = 0; k0 < Kp; k0 += 32) {
        size_t gA0 = (size_t)(m0 + r0) * Kp + k0 + s0 * 8;
        size_t gA1 = (size_t)(m0 + r0 + 64) * Kp + k0 + s0 * 8;
        size_t gB0 = (size_t)(n0 + r0) * Kp + k0 + s0 * 8;
        size_t gB1 = (size_t)(n0 + r0 + 64) * Kp + k0 + s0 * 8;
        short8v ah0, ah1, al0, al1;
        if constexpr (ASPLIT) {
            ah0 = *(const short8v*)(Ahi + gA0);
            ah1 = *(const short8v*)(Ahi + gA1);
            al0 = *(const short8v*)(Alo + gA0);
            al1 = *(const short8v*)(Alo + gA1);
        } else {
            u16x8 a0 = *(const u16x8*)(A16 + gA0);
            u16x8 a1 = *(const u16x8*)(A16 + gA1);
            #pragma unroll
            for (int j = 0; j < 8; ++j) {
                float f0 = h2f(a0[j]);
                u16 h0 = f2bf(f0);
                ah0[j] = (short)h0;
                al0[j] = (short)f2bf(f0 - bf2f(h0));
                float f1 = h2f(a1[j]);
                u16 h1 = f2bf(f1);
                ah1[j] = (short)h1;
                al1[j] = (short)f2bf(f1 - bf2f(h1));
            }
        }
        short8v bh0 = *(const short8v*)(Bhi + gB0);
        short8v bh1 = *(const short8v*)(Bhi + gB1);
        short8v bl0 = *(const short8v*)(Blo + gB0);
        short8v bl1 = *(const short8v*)(Blo + gB1);
        __syncthreads();
        ((short8v*)sAh)[w0] = ah0; ((short8v*)sAh)[w1] = ah1;
        ((short8v*)sAl)[w0] = al0; ((short8v*)sAl)[w1] = al1;
        ((short8v*)sBh)[w0] = bh0; ((short8v*)sBh)[w1] = bh1;
        ((short8v*)sBl)[w0] = bl0; ((short8v*)sBl)[w1] = bl1;
        __syncthreads();
        FragU fah[4], fal[4], fbh[4], fbl[4];
        #pragma unroll
        for (int mf = 0; mf < 4; ++mf) {
            int rr = wm * 64 + mf * 16 + l15;
            int idx = swz(rr, lg);
            fah[mf].s = ((const short8v*)sAh)[idx];
            fal[mf].s = ((const short8v*)sAl)[idx];
        }
        #pragma unroll
        for (int nf = 0; nf < 4; ++nf) {
            int rr = wn * 64 + nf * 16 + l15;
            int idx = swz(rr, lg);
            fbh[nf].s = ((const short8v*)sBh)[idx];
            fbl[nf].s = ((const short8v*)sBl)[idx];
        }
        #pragma unroll
        for (int mf = 0; mf < 4; ++mf) {
            #pragma unroll
            for (int nf = 0; nf < 4; ++nf) {
                acc[mf][nf] = __builtin_amdgcn_mfma_f32_16x16x32_bf16(fah[mf].b, fbh[nf].b, acc[mf][nf], 0, 0, 0);
                acc[mf][nf] = __builtin_amdgcn_mfma_f32_16x16x32_bf16(fah[mf].b, fbl[nf].b, acc[mf][nf], 0, 0, 0);
                acc[mf][nf] = __builtin_amdgcn_mfma_f32_16x16x32_bf16(fal[mf].b, fbh[nf].b, acc[mf][nf], 0, 0, 0);
            }
        }
    }
    #pragma unroll
    for (int mf = 0; mf < 4; ++mf) {
        #pragma unroll
        for (int nf = 0; nf < 4; ++nf) {
            int colg = n0 + wn * 64 + nf * 16 + l15;
            if (colg >= Ncols) continue;
            #pragma unroll
            for (int r = 0; r < 4; ++r) {
                int rowg = m0 + wm * 64 + mf * 16 + lg * 4 + r;
                if (rowg < M) C16[(size_t)rowg * Ncols + colg] = f2h(acc[mf][nf][r]);
            }
        }
    }
}

// ---------------- lean agg: fp16 table + streaming weights ----------------
// wave per node; lane owns 8 consecutive fp16 channels (16B load/edge).
// Single dependent load level (col -> hf); w[e*8+h] is an e-indexed stream.

template <int H, int C, bool RELU, bool F16OUT>
__global__ __launch_bounds__(256) void aggL_k(
    const u16* __restrict__ hf, const float* __restrict__ w,
    const float* __restrict__ bias,
    const int* __restrict__ row_ptr, const int* __restrict__ col,
    float* __restrict__ outf, u16* __restrict__ oh16, int n)
{
    constexpr int HC = H * C;
    constexpr int LACT = HC / 8;
    const int wv = threadIdx.x >> 6, lane = threadIdx.x & 63;
    const int i = blockIdx.x * 4 + wv;
    if (i >= n) return;
    const int ch0 = lane * 8;
    const bool act = lane < LACT;
    const int h = act ? (ch0 / C) : 0;
    const bool lead = act && ((ch0 % C) == 0);
    const int beg = row_ptr[i], end = row_ptr[i + 1];
    float acc[8] = {};
    float dp = 0.f;
    if (act) {
        int e = beg;
        for (; e + 2 <= end; e += 2) {
            int sA = col[e], sB = col[e + 1];
            float wA = w[(size_t)e * 8 + h];
            float wB = w[(size_t)(e + 1) * 8 + h];
            u16x8 vA = *(const u16x8*)(hf + (size_t)sA * HC + ch0);
            u16x8 vB = *(const u16x8*)(hf + (size_t)sB * HC + ch0);
            #pragma unroll
            for (int j = 0; j < 8; ++j)
                acc[j] += wA * h2f(vA[j]) + wB * h2f(vB[j]);
            if (lead) dp += wA + wB;
        }
        if (e < end) {
            int sA = col[e];
            float wA = w[(size_t)e * 8 + h];
            u16x8 vA = *(const u16x8*)(hf + (size_t)sA * HC + ch0);
            #pragma unroll
            for (int j = 0; j < 8; ++j)
                acc[j] += wA * h2f(vA[j]);
            if (lead) dp += wA;
        }
    }
    const float den = __shfl(dp, h * (C / 8)) + 1e-16f;
    if (act) {
        float o[8];
        #pragma unroll
        for (int j = 0; j < 8; ++j) {
            float v = acc[j] / den + bias[ch0 + j];
            if (RELU) v = fmaxf(v, 0.f);
            o[j] = v;
        }
        size_t base = (size_t)i * HC + ch0;
        if constexpr (F16OUT) {
            u16x8 po;
            #pragma unroll
            for (int j = 0; j < 8; ++j) po[j] = f2h(o[j]);
            *(u16x8*)(oh16 + base) = po;
        } else {
            float4 q0; q0.x = o[0]; q0.y = o[1]; q0.z = o[2]; q0.w = o[3];
            float4 q1; q1.x = o[4]; q1.y = o[5]; q1.z = o[6]; q1.w = o[7];
            *(float4*)(outf + base) = q0;
            *(float4*)(outf + base + 4) = q1;
        }
    }
}

// ---------------------------------------------------------------------------

extern "C" void kernel_launch(void* const* d_in, const int* in_sizes, int n_in,
                              void* d_out, int out_size, void* d_ws, size_t ws_size,
                              hipStream_t stream) {
    const float* x   = (const float*)d_in[0];
    const int*   ei  = (const int*)d_in[1];
    const float* W1  = (const float*)d_in[2];
    const float* a1s = (const float*)d_in[3];
    const float* a1d = (const float*)d_in[4];
    const float* b1  = (const float*)d_in[5];
    const float* W2  = (const float*)d_in[6];
    const float* a2s = (const float*)d_in[7];
    const float* a2d = (const float*)d_in[8];
    const float* b2  = (const float*)d_in[9];
    const float* W3  = (const float*)d_in[10];
    const float* a3s = (const float*)d_in[11];
    const float* a3d = (const float*)d_in[12];
    const float* b3  = (const float*)d_in[13];
    float* out = (float*)d_out;

    const int Nn = in_sizes[0] / NFEAT;   // 30000
    const int E  = in_sizes[1] / 2;       // 480000
    const int Et = E + Nn;
    const int NB = (Nn + 255) / 256;      // 118 scan blocks
    const int* srcp = ei;
    const int* dstp = ei + E;

    char* ws = (char*)d_ws;
    size_t off = 0;
    auto carve = [&](size_t bytes) -> char* {
        char* p = ws + off;
        off += (bytes + 255) & ~(size_t)255;
        return p;
    };
    u16*   hbuf16 = (u16*)carve((size_t)MPAD * 448 * 2);   // h~ fp16 (all layers)
    u16*   hA16  = (u16*)carve((size_t)MPAD * 448 * 2);    // h1 fp16
    u16*   hB16  = (u16*)carve((size_t)MPAD * 384 * 2);    // h2 fp16
    u16*   Xhi   = (u16*)carve((size_t)MPAD * 160 * 2);
    u16*   Xlo   = (u16*)carve((size_t)MPAD * 160 * 2);
    u16*   Wthi  = (u16*)carve((size_t)352256 * 2);
    u16*   Wtlo  = (u16*)carve((size_t)352256 * 2);
    float* wbuf  = (float*)carve((size_t)Et * 8 * 4);
    int*   col   = (int*)carve((size_t)Et * 4);
    int*   dstc  = (int*)carve((size_t)Et * 4);
    int* row_ptr = (int*)carve((size_t)(Nn + 1) * 4);
    int*   cnt   = (int*)carve((size_t)Nn * 4);
    int*   bsum  = (int*)carve((size_t)NB * 4);
    int*   bofs  = (int*)carve((size_t)(NB + 1) * 4);
    float* aA    = (float*)carve((size_t)Nn * 8 * 4);
    float* dA    = (float*)carve((size_t)Nn * 8 * 4);
    float* aB    = (float*)carve((size_t)Nn * 8 * 4);
    float* dB    = (float*)carve((size_t)Nn * 8 * 4);
    float* Ps    = (float*)carve((size_t)992 * 8 * 4);
    float* Pd    = (float*)carve((size_t)992 * 8 * 4);
    (void)ws_size;

    const int nb4 = (Nn + 3) / 4;   // 7500
    const int mg  = MPAD / 128;     // 235
    const int PREP_TOT = MPAD * 160 + 352256 + 992 * 8 + (MPAD - 30000) * 448 + (MPAD - 30000) * 384;

    // ---- CSR (plain dst keys) ----
    hipMemsetAsync(cnt, 0, (size_t)Nn * 4, stream);
    hist_k<<<(Et + 255) / 256, 256, 0, stream>>>(dstp, cnt, E, Nn);
    bsum_k<<<NB, 256, 0, stream>>>(cnt, bsum, Nn);
    bscan_k<<<1, 1024, 0, stream>>>(bsum, bofs, NB);
    scanw_k<<<NB, 256, 0, stream>>>(cnt, bofs, row_ptr, Nn);
    hipMemsetAsync(cnt, 0, (size_t)Nn * 4, stream);
    scatter_k<<<(Et + 255) / 256, 256, 0, stream>>>(srcp, dstp, row_ptr, cnt, col, dstc, E, Nn);

    // ---- fused prep (independent of CSR) ----
    prep_k<<<(PREP_TOT + 255) / 256, 256, 0, stream>>>(
        x, W1, a1s, a1d, W2, a2s, a2d, W3, a3s, a3d,
        Xhi, Xlo, Wthi, Wtlo, Ps, Pd, hA16, hB16, Nn);

    // ---- layer 1: x(129) -> 7x64 ----
    alpha1_k<<<nb4, 256, 0, stream>>>(x, Ps, Pd, aA, dA, Nn);
    edgew_k<<<(Et * 8 + 255) / 256, 256, 0, stream>>>(aA, dA, col, dstc, wbuf, Et);
    gemm16<true><<<dim3(4, mg), 256, 0, stream>>>(Xhi, Xlo, nullptr, Wthi, Wtlo,
                                                  hbuf16, Nn, 448, 160);
    aggL_k<7, 64, true, true><<<nb4, 256, 0, stream>>>(
        hbuf16, wbuf, b1, row_ptr, col, nullptr, hA16, Nn);
    alphaproj_k<7><<<nb4, 256, 0, stream>>>(hA16, Ps + 1280, Pd + 1280, aB, dB, Nn);

    // ---- layer 2: 448 -> 6x64 ----
    edgew_k<<<(Et * 8 + 255) / 256, 256, 0, stream>>>(aB, dB, col, dstc, wbuf, Et);
    gemm16<false><<<dim3(3, mg), 256, 0, stream>>>(nullptr, nullptr, hA16,
                                                   Wthi + 81920, Wtlo + 81920,
                                                   hbuf16, Nn, 384, 448);
    aggL_k<6, 64, true, true><<<nb4, 256, 0, stream>>>(
        hbuf16, wbuf, b2, row_ptr, col, nullptr, hB16, Nn);
    alphaproj_k<6><<<nb4, 256, 0, stream>>>(hB16, Ps + 4864, Pd + 4864, aA, dA, Nn);

    // ---- layer 3: 384 -> 6x40 ----
    edgew_k<<<(Et * 8 + 255) / 256, 256, 0, stream>>>(aA, dA, col, dstc, wbuf, Et);
    gemm16<false><<<dim3(2, mg), 256, 0, stream>>>(nullptr, nullptr, hB16,
                                                   Wthi + 253952, Wtlo + 253952,
                                                   hbuf16, Nn, 240, 384);
    aggL_k<6, 40, false, false><<<nb4, 256, 0, stream>>>(
        hbuf16, wbuf, b3, row_ptr, col, out, nullptr, Nn);
}